// Round 14
// baseline (507.482 us; speedup 1.0000x reference)
//
#include <hip/hip_runtime.h>
#include <hip/hip_bf16.h>
#include <math.h>

// HelicalGNNFrontend: 2-layer GATv2 (heads=1, self-loops, mean loop edge_attr)
// N=50000, E=800000, NODE_DIM=HID=128, EDGE_DIM=32.
//
// Round 14: R12b base (f16 fdot2 eproj, scalar s_load edge stream, 2-wide
// pipeline) + occupancy: 2 nodes per 128-thread block (1-wave workgroups
// were wg/CU-capped at ~58% occ; max-of-2 Poisson imbalance ~7% << gain).
// Node id pinned to SGPR via readfirstlane (R7-proven to keep scalar path).
// Micro: leaky = fmaxf(v, 0.2v); logits in exp2 domain (att pre-scaled 1/ln2).

#define HIP_N 50000
#define HIP_E 800000
#define HIP_H 128
#define HIP_ED 32
#define NEG_SLOPE 0.2f
#define RESCALE_THR_LOG2 11.5416f   // 8 / ln2
#define LINB ((HIP_N + 31) / 32)          // 1563 lin blocks
#define SCATB ((HIP_E + 255) / 256)       // 3125 scatter blocks
#define INV_LN2 1.4426950408889634f

typedef __fp16 h2 __attribute__((ext_vector_type(2)));

__device__ __forceinline__ h2 u2h(unsigned int u) {
    union { unsigned int u; h2 h; } c; c.u = u; return c.h;
}
__device__ __forceinline__ unsigned int pkh(float a, float b) {
    union { h2 h; unsigned int u; } c;
    c.h = __builtin_amdgcn_cvt_pkrtz(a, b);
    return c.u;
}

// ---------------- edge-index dtype detection ----------------
__global__ void k_detect(const int* __restrict__ ei, int* __restrict__ is32) {
    int j = blockIdx.x * blockDim.x + threadIdx.x;   // j in [0, 4096)
    if (j < 4096) {
        if (ei[2 * j + 1] != 0) atomicOr(is32, 1);
    }
}

__device__ __forceinline__ int fetch_idx(const int* __restrict__ ei, int is32, long long pos) {
    return is32 ? ei[pos] : ei[2 * pos];  // little-endian low word for int64
}

// ---------------- CSR build ----------------
__global__ void k_hist(const int* __restrict__ ei, const int* __restrict__ flag,
                       int* __restrict__ deg) {
    int is32 = *flag;
    int e = blockIdx.x * blockDim.x + threadIdx.x;
    if (e < HIP_E) {
        int d = fetch_idx(ei, is32, (long long)HIP_E + e);
        atomicAdd(&deg[d], 1);
    }
}

#define SCAN_TILE 1024
#define SCAN_NB ((HIP_N + SCAN_TILE - 1) / SCAN_TILE)   // 49

__global__ __launch_bounds__(256) void k_scan1(const int* __restrict__ deg,
                                               int* __restrict__ bsums) {
    __shared__ int ws[4];
    int b = blockIdx.x, t = threadIdx.x;
    int base = b * SCAN_TILE;
    int v = 0;
#pragma unroll
    for (int j = 0; j < 4; ++j) {
        int i = base + t + 256 * j;
        if (i < HIP_N) v += deg[i];
    }
#pragma unroll
    for (int off = 32; off > 0; off >>= 1) v += __shfl_xor(v, off);
    int lane = t & 63, wid = t >> 6;
    if (lane == 0) ws[wid] = v;
    __syncthreads();
    if (t == 0) bsums[b] = ws[0] + ws[1] + ws[2] + ws[3];
}

__global__ __launch_bounds__(64) void k_scan2(const int* __restrict__ bsums,
                                              int* __restrict__ bscan) {
    int t = threadIdx.x;
    int v = (t < SCAN_NB) ? bsums[t] : 0;
    int incl = v;
#pragma unroll
    for (int off = 1; off < 64; off <<= 1) {
        int u = __shfl_up(incl, off);
        if (t >= off) incl += u;
    }
    if (t < SCAN_NB) bscan[t] = incl - v;   // exclusive
}

__global__ __launch_bounds__(1024) void k_scan3(const int* __restrict__ deg,
                                                const int* __restrict__ bscan,
                                                int* __restrict__ offs,
                                                int* __restrict__ cursor) {
    __shared__ int wsum[16];
    int b = blockIdx.x, t = threadIdx.x;
    int i = b * SCAN_TILE + t;
    int lane = t & 63, wid = t >> 6;
    int v = (i < HIP_N) ? deg[i] : 0;
    int incl = v;
#pragma unroll
    for (int off = 1; off < 64; off <<= 1) {
        int u = __shfl_up(incl, off);
        if (lane >= off) incl += u;
    }
    if (lane == 63) wsum[wid] = incl;
    __syncthreads();
    if (wid == 0 && lane < 16) {
        int w = wsum[lane];
#pragma unroll
        for (int off = 1; off < 16; off <<= 1) {
            int u = __shfl_up(w, off);
            if (lane >= off) w += u;
        }
        wsum[lane] = w;   // inclusive over waves
    }
    __syncthreads();
    int baseadd = bscan[b] + (wid > 0 ? wsum[wid - 1] : 0);
    int excl = baseadd + incl - v;
    if (i < HIP_N) {
        offs[i] = excl;
        cursor[i] = excl;
        if (i == HIP_N - 1) offs[HIP_N] = excl + v;
    }
}

// ---------------- shared bodies ----------------
// dual GEMM body (R8-proven scalar form)
__device__ __forceinline__ void lin_body(const float* __restrict__ h,
                                         const float* __restrict__ Wl,
                                         const float* __restrict__ bl,
                                         const float* __restrict__ Wr,
                                         const float* __restrict__ br,
                                         float* __restrict__ xl,
                                         float* __restrict__ xr, int n, int blk) {
    __shared__ float tile[32][128];
    int rb = blk * 32;
    int tid = threadIdx.x;
    for (int j = 0; j < 16; ++j) {
        int idx = j * 256 + tid;
        int r = idx >> 7, c = idx & 127;
        int row = rb + r;
        tile[r][c] = (row < n) ? h[(size_t)row * 128 + c] : 0.f;
    }
    __syncthreads();
    int c = tid & 127, g = tid >> 7;
    float accl[16], accr[16];
#pragma unroll
    for (int r = 0; r < 16; ++r) { accl[r] = 0.f; accr[r] = 0.f; }
    for (int d4 = 0; d4 < 32; ++d4) {
        int d = d4 * 4;
        float wl0 = Wl[(d + 0) * 128 + c];
        float wl1 = Wl[(d + 1) * 128 + c];
        float wl2 = Wl[(d + 2) * 128 + c];
        float wl3 = Wl[(d + 3) * 128 + c];
        float wr0 = Wr[(d + 0) * 128 + c];
        float wr1 = Wr[(d + 1) * 128 + c];
        float wr2 = Wr[(d + 2) * 128 + c];
        float wr3 = Wr[(d + 3) * 128 + c];
#pragma unroll
        for (int r = 0; r < 16; ++r) {
            const float4 hv = *(const float4*)&tile[g * 16 + r][d];
            accl[r] += hv.x * wl0 + hv.y * wl1 + hv.z * wl2 + hv.w * wl3;
            accr[r] += hv.x * wr0 + hv.y * wr1 + hv.z * wr2 + hv.w * wr3;
        }
    }
    float bbl = bl[c], bbr = br[c];
    for (int r = 0; r < 16; ++r) {
        int row = rb + g * 16 + r;
        if (row < n) {
            xl[(size_t)row * 128 + c] = accl[r] + bbl;
            xr[(size_t)row * 128 + c] = accr[r] + bbr;
        }
    }
}

// scatter body: e_src[pos]=src, ea_h[pos]= half2-packed ea row (64B)
__device__ __forceinline__ void scatter_body(const int* __restrict__ ei, int is32,
                                             int* __restrict__ cursor,
                                             int* __restrict__ e_src,
                                             const float* __restrict__ ea,
                                             unsigned int* __restrict__ ea_h, int e) {
    if (e < HIP_E) {
        int s = fetch_idx(ei, is32, e);
        int d = fetch_idx(ei, is32, (long long)HIP_E + e);
        int pos = atomicAdd(&cursor[d], 1);
        e_src[pos] = s;
        const float4* src4 = (const float4*)(ea + (size_t)e * HIP_ED);
        float4 s0 = src4[0], s1 = src4[1], s2 = src4[2], s3 = src4[3];
        float4 s4 = src4[4], s5 = src4[5], s6 = src4[6], s7 = src4[7];
        uint4* dst = (uint4*)(ea_h + (size_t)pos * 16);
        dst[0] = make_uint4(pkh(s0.x, s0.y), pkh(s0.z, s0.w),
                            pkh(s1.x, s1.y), pkh(s1.z, s1.w));
        dst[1] = make_uint4(pkh(s2.x, s2.y), pkh(s2.z, s2.w),
                            pkh(s3.x, s3.y), pkh(s3.z, s3.w));
        dst[2] = make_uint4(pkh(s4.x, s4.y), pkh(s4.z, s4.w),
                            pkh(s5.x, s5.y), pkh(s5.z, s5.w));
        dst[3] = make_uint4(pkh(s6.x, s6.y), pkh(s6.z, s6.w),
                            pkh(s7.x, s7.y), pkh(s7.z, s7.w));
    }
}

// fat kernel: blocks [0, LINB) do layer-1 lin; blocks [LINB, LINB+SCATB) scatter
__global__ __launch_bounds__(256) void k_fat1(
    const float* __restrict__ x, const float* __restrict__ Wl,
    const float* __restrict__ bl, const float* __restrict__ Wr,
    const float* __restrict__ br, float* __restrict__ xl, float* __restrict__ xr,
    const int* __restrict__ ei, const int* __restrict__ flag,
    int* __restrict__ cursor, int* __restrict__ e_src,
    const float* __restrict__ ea, unsigned int* __restrict__ ea_h) {
    if (blockIdx.x < LINB) {
        lin_body(x, Wl, bl, Wr, br, xl, xr, HIP_N, blockIdx.x);
    } else {
        int e = (blockIdx.x - LINB) * 256 + threadIdx.x;
        scatter_body(ei, *flag, cursor, e_src, ea, ea_h, e);
    }
}

__global__ __launch_bounds__(256) void k_lin(const float* __restrict__ h,
                                             const float* __restrict__ Wl,
                                             const float* __restrict__ bl,
                                             const float* __restrict__ Wr,
                                             const float* __restrict__ br,
                                             float* __restrict__ xl,
                                             float* __restrict__ xr, int n) {
    lin_body(h, Wl, bl, Wr, br, xl, xr, n, blockIdx.x);
}

// ---------------- weight composition (folds k_emb into layer-1) ----------------
__global__ __launch_bounds__(128) void k_compose(
    const float* __restrict__ Wemb, const float* __restrict__ bemb,
    const float* __restrict__ Wl, const float* __restrict__ bl,
    const float* __restrict__ Wr,
    float* __restrict__ Wlf, float* __restrict__ blf,
    float* __restrict__ Wrf, float* __restrict__ brf,
    float* __restrict__ zerob) {
    int b = blockIdx.x, c = threadIdx.x;
    if (b < 128) {
        float acc = 0.f;
        for (int k = 0; k < 128; ++k) acc += Wemb[b * 128 + k] * Wl[k * 128 + c];
        Wlf[b * 128 + c] = acc;
    } else if (b < 256) {
        int r = b - 128;
        float acc = 0.f;
        for (int k = 0; k < 128; ++k) acc += Wemb[r * 128 + k] * Wr[k * 128 + c];
        Wrf[r * 128 + c] = acc;
    } else if (b == 256) {
        float acc = bl[c];
        for (int k = 0; k < 128; ++k) acc += bemb[k] * Wl[k * 128 + c];
        blf[c] = acc;
    } else {
        float acc = 0.f;
        for (int k = 0; k < 128; ++k) acc += bemb[k] * Wr[k * 128 + c];
        brf[c] = acc;
        zerob[c] = 0.f;
    }
}

// pack We (32x128 fp32) -> Wepk (2048 uint: half2 over d-pairs)
// Wepk[d2*128 + j*64 + t] = half2(We[2*d2][2*t+j], We[2*d2+1][2*t+j])
__global__ __launch_bounds__(256) void k_packwe(const float* __restrict__ We1,
                                                const float* __restrict__ We2,
                                                unsigned int* __restrict__ P1,
                                                unsigned int* __restrict__ P2) {
    int idx = blockIdx.x * 256 + threadIdx.x;     // [0, 4096)
    if (idx < 4096) {
        const float* We = (idx < 2048) ? We1 : We2;
        unsigned int* P = (idx < 2048) ? P1 : P2;
        int r = idx & 2047;
        int d2 = r >> 7, rem = r & 127;
        int j = rem >> 6, t = rem & 63;
        int col = 2 * t + j;
        P[r] = pkh(We[(2 * d2) * 128 + col], We[(2 * d2 + 1) * 128 + col]);
    }
}

// ---------------- fused per-node online softmax + aggregation ----------------
// TWO nodes per 128-thread block (one wave each); node id pinned to SGPR via
// readfirstlane so per-edge addresses stay on the scalar s_load path.
// eproj: 32x fdot2 (f16 pairs, fp32 acc). Logits in exp2 domain (att
// pre-scaled by 1/ln2). leaky_relu(v) = max(v, 0.2v). 2-wide edge pipeline.
__global__ __launch_bounds__(128) void k_node_fused(
    const int* __restrict__ offs, const int* __restrict__ e_src,
    const unsigned int* __restrict__ ea_h,
    const unsigned int* __restrict__ Wepk, const float* __restrict__ att,
    const float* __restrict__ xl, const float* __restrict__ xr,
    const float* __restrict__ bo, float* __restrict__ hout) {
    int i = __builtin_amdgcn_readfirstlane(blockIdx.x * 2 + (threadIdx.x >> 6));
    int t = threadIdx.x & 63;     // lane, owns feature dims (2t, 2t+1)
    if (i >= HIP_N) return;

    // We pairs: wxK = (We[2K][2t], We[2K+1][2t]), wyK = same for dim 2t+1
    h2 wx00 = u2h(Wepk[ 0*128 + t]),      wy00 = u2h(Wepk[ 0*128 + 64 + t]);
    h2 wx01 = u2h(Wepk[ 1*128 + t]),      wy01 = u2h(Wepk[ 1*128 + 64 + t]);
    h2 wx02 = u2h(Wepk[ 2*128 + t]),      wy02 = u2h(Wepk[ 2*128 + 64 + t]);
    h2 wx03 = u2h(Wepk[ 3*128 + t]),      wy03 = u2h(Wepk[ 3*128 + 64 + t]);
    h2 wx04 = u2h(Wepk[ 4*128 + t]),      wy04 = u2h(Wepk[ 4*128 + 64 + t]);
    h2 wx05 = u2h(Wepk[ 5*128 + t]),      wy05 = u2h(Wepk[ 5*128 + 64 + t]);
    h2 wx06 = u2h(Wepk[ 6*128 + t]),      wy06 = u2h(Wepk[ 6*128 + 64 + t]);
    h2 wx07 = u2h(Wepk[ 7*128 + t]),      wy07 = u2h(Wepk[ 7*128 + 64 + t]);
    h2 wx08 = u2h(Wepk[ 8*128 + t]),      wy08 = u2h(Wepk[ 8*128 + 64 + t]);
    h2 wx09 = u2h(Wepk[ 9*128 + t]),      wy09 = u2h(Wepk[ 9*128 + 64 + t]);
    h2 wx10 = u2h(Wepk[10*128 + t]),      wy10 = u2h(Wepk[10*128 + 64 + t]);
    h2 wx11 = u2h(Wepk[11*128 + t]),      wy11 = u2h(Wepk[11*128 + 64 + t]);
    h2 wx12 = u2h(Wepk[12*128 + t]),      wy12 = u2h(Wepk[12*128 + 64 + t]);
    h2 wx13 = u2h(Wepk[13*128 + t]),      wy13 = u2h(Wepk[13*128 + 64 + t]);
    h2 wx14 = u2h(Wepk[14*128 + t]),      wy14 = u2h(Wepk[14*128 + 64 + t]);
    h2 wx15 = u2h(Wepk[15*128 + t]),      wy15 = u2h(Wepk[15*128 + 64 + t]);

    float2 attv = ((const float2*)att)[t];
    attv.x *= INV_LN2; attv.y *= INV_LN2;   // exp2-domain logits
    float2 bov  = ((const float2*)bo)[t];
    float2 xri  = ((const float2*)(xr + (size_t)i * HIP_H))[t];
    float2 xli  = ((const float2*)(xl + (size_t)i * HIP_H))[t];

    float m = -1e30f;
    float denom = 0.f;
    float accx = 0.f, accy = 0.f;
    float epsx = 0.f, epsy = 0.f;   // sum of per-edge eproj (for self-loop)

    int o0 = offs[i], o1 = offs[i + 1];     // uniform -> s_load
    int cnt = o1 - o0;
    int pairs = cnt >> 1;
    const float2* xl2 = (const float2*)xl;

#define DOTP(EX, EY, U, K)                                            \
    EX = __builtin_amdgcn_fdot2(u2h(U), wx##K, EX, false);            \
    EY = __builtin_amdgcn_fdot2(u2h(U), wy##K, EY, false);

#define EPROJ(EX, EY, P)                                              \
    {                                                                 \
        uint4 q0 = ((const uint4*)(P))[0];                            \
        uint4 q1 = ((const uint4*)(P))[1];                            \
        uint4 q2 = ((const uint4*)(P))[2];                            \
        uint4 q3 = ((const uint4*)(P))[3];                            \
        DOTP(EX, EY, q0.x, 00) DOTP(EX, EY, q0.y, 01)                 \
        DOTP(EX, EY, q0.z, 02) DOTP(EX, EY, q0.w, 03)                 \
        DOTP(EX, EY, q1.x, 04) DOTP(EX, EY, q1.y, 05)                 \
        DOTP(EX, EY, q1.z, 06) DOTP(EX, EY, q1.w, 07)                 \
        DOTP(EX, EY, q2.x, 08) DOTP(EX, EY, q2.y, 09)                 \
        DOTP(EX, EY, q2.z, 10) DOTP(EX, EY, q2.w, 11)                 \
        DOTP(EX, EY, q3.x, 12) DOTP(EX, EY, q3.y, 13)                 \
        DOTP(EX, EY, q3.z, 14) DOTP(EX, EY, q3.w, 15)                 \
    }

    // pair-ahead prefetch of the two xl gathers
    float2 xA = make_float2(0.f, 0.f), xB = make_float2(0.f, 0.f);
    if (pairs > 0) {
        int s0 = e_src[o0];                 // uniform -> s_load
        int s1 = e_src[o0 + 1];
        xA = xl2[(size_t)s0 * 64 + t];
        xB = xl2[(size_t)s1 * 64 + t];
    }

    for (int pp = 0; pp < pairs; ++pp) {
        int e = o0 + 2 * pp;
        float2 x0 = xA, x1 = xB;
        if (pp + 1 < pairs) {               // prefetch next pair's gathers
            int s0 = e_src[e + 2];
            int s1 = e_src[e + 3];
            xA = xl2[(size_t)s0 * 64 + t];
            xB = xl2[(size_t)s1 * 64 + t];
        }
        const unsigned int* er = ea_h + (size_t)e * 16;   // uniform (2 rows, 32 dw)
        float ex0 = 0.f, ey0 = 0.f, ex1 = 0.f, ey1 = 0.f;
        EPROJ(ex0, ey0, er)
        EPROJ(ex1, ey1, er + 16)
        epsx += ex0 + ex1; epsy += ey0 + ey1;
        float vx0 = x0.x + xri.x + ex0, vy0 = x0.y + xri.y + ey0;
        float vx1 = x1.x + xri.x + ex1, vy1 = x1.y + xri.y + ey1;
        vx0 = fmaxf(vx0, NEG_SLOPE * vx0);   // leaky_relu as single max
        vy0 = fmaxf(vy0, NEG_SLOPE * vy0);
        vx1 = fmaxf(vx1, NEG_SLOPE * vx1);
        vy1 = fmaxf(vy1, NEG_SLOPE * vy1);
        float p0 = vx0 * attv.x + vy0 * attv.y;
        float p1 = vx1 * attv.x + vy1 * attv.y;
#pragma unroll
        for (int off = 32; off > 0; off >>= 1) {   // interleaved chains
            p0 += __shfl_xor(p0, off);
            p1 += __shfl_xor(p1, off);
        }
        float pm = fmaxf(p0, p1);
        if (pm > m + RESCALE_THR_LOG2) {    // defer-max rescale (wave-uniform)
            float sc = exp2f(m - pm);
            accx *= sc; accy *= sc; denom *= sc;
            m = pm;
        }
        float wA = exp2f(p0 - m);
        float wB = exp2f(p1 - m);
        accx += wA * x0.x + wB * x1.x;
        accy += wA * x0.y + wB * x1.y;
        denom += wA + wB;
    }

    if (cnt & 1) {                          // tail edge
        int e = o1 - 1;
        int s = e_src[e];
        float2 x0 = xl2[(size_t)s * 64 + t];
        const unsigned int* er = ea_h + (size_t)e * 16;
        float ex = 0.f, ey = 0.f;
        EPROJ(ex, ey, er)
        epsx += ex; epsy += ey;
        float vx = x0.x + xri.x + ex;
        float vy = x0.y + xri.y + ey;
        vx = fmaxf(vx, NEG_SLOPE * vx);
        vy = fmaxf(vy, NEG_SLOPE * vy);
        float p = vx * attv.x + vy * attv.y;
#pragma unroll
        for (int off = 32; off > 0; off >>= 1) p += __shfl_xor(p, off);
        if (p > m + RESCALE_THR_LOG2) {
            float sc = exp2f(m - p);
            accx *= sc; accy *= sc; denom *= sc;
            m = p;
        }
        float w = exp2f(p - m);
        accx += w * x0.x;
        accy += w * x0.y;
        denom += w;
    }
#undef EPROJ
#undef DOTP

    // ---- self-loop (last): loop_attr projection = mean of eproj ----
    float invdeg = 1.f / fmaxf((float)cnt, 1.f);
    float sx = xli.x + xri.x + epsx * invdeg;
    float sy = xli.y + xri.y + epsy * invdeg;
    sx = fmaxf(sx, NEG_SLOPE * sx);
    sy = fmaxf(sy, NEG_SLOPE * sy);
    float ps = sx * attv.x + sy * attv.y;
#pragma unroll
    for (int off = 32; off > 0; off >>= 1) ps += __shfl_xor(ps, off);

    float mm = fmaxf(m, ps);
    float wf = exp2f(m - mm);
    float ws = exp2f(ps - mm);
    denom = denom * wf + ws;
    accx = accx * wf + ws * xli.x;
    accy = accy * wf + ws * xli.y;

    float ox = accx / denom + bov.x;
    float oy = accy / denom + bov.y;
    float2 o;
    o.x = ox / (1.f + __expf(-ox));
    o.y = oy / (1.f + __expf(-oy));
    ((float2*)(hout + (size_t)i * HIP_H))[t] = o;
}

// ---------------- host launch ----------------
extern "C" void kernel_launch(void* const* d_in, const int* in_sizes, int n_in,
                              void* d_out, int out_size, void* d_ws, size_t ws_size,
                              hipStream_t stream) {
    const float* x      = (const float*)d_in[0];
    const int*   ei     = (const int*)d_in[1];
    const float* ea     = (const float*)d_in[2];
    const float* W_emb  = (const float*)d_in[3];
    const float* b_emb  = (const float*)d_in[4];
    const float* Wl1    = (const float*)d_in[5];
    const float* bl1    = (const float*)d_in[6];
    const float* Wr1    = (const float*)d_in[7];
    const float* We1    = (const float*)d_in[8];
    const float* att1   = (const float*)d_in[9];
    const float* bo1    = (const float*)d_in[10];
    const float* Wl2    = (const float*)d_in[11];
    const float* bl2    = (const float*)d_in[12];
    const float* Wr2    = (const float*)d_in[13];
    const float* We2    = (const float*)d_in[14];
    const float* att2   = (const float*)d_in[15];
    const float* bo2    = (const float*)d_in[16];
    float* out = (float*)d_out;

    char* p = (char*)d_ws;
    auto carve = [&](size_t bytes) {
        void* q = (void*)p;
        p += (bytes + 255) / 256 * 256;
        return q;
    };
    float* h        = (float*)carve((size_t)HIP_N * 128 * 4);
    float* xl       = (float*)carve((size_t)HIP_N * 128 * 4);
    float* xr       = (float*)carve((size_t)HIP_N * 128 * 4);
    unsigned int* ea_h = (unsigned int*)carve((size_t)HIP_E * 16 * 4);
    int*   deg      = (int*)carve((size_t)HIP_N * 4);
    int*   offs     = (int*)carve((size_t)(HIP_N + 1) * 4);
    int*   cursor   = (int*)carve((size_t)HIP_N * 4);
    int*   e_src    = (int*)carve((size_t)HIP_E * 4);
    int*   flag     = (int*)carve(256);
    int*   bsums    = (int*)carve((size_t)SCAN_NB * 4);
    int*   bscan    = (int*)carve((size_t)SCAN_NB * 4);
    float* Wl1f     = (float*)carve(128 * 128 * 4);
    float* Wr1f     = (float*)carve(128 * 128 * 4);
    float* bl1f     = (float*)carve(128 * 4);
    float* br1f     = (float*)carve(128 * 4);
    float* zerob    = (float*)carve(128 * 4);
    unsigned int* Wepk1 = (unsigned int*)carve(2048 * 4);
    unsigned int* Wepk2 = (unsigned int*)carve(2048 * 4);

    hipMemsetAsync(deg, 0, (size_t)HIP_N * 4, stream);
    hipMemsetAsync(flag, 0, 4, stream);

    k_detect<<<16, 256, 0, stream>>>(ei, flag);
    k_hist<<<(HIP_E + 255) / 256, 256, 0, stream>>>(ei, flag, deg);
    k_scan1<<<SCAN_NB, 256, 0, stream>>>(deg, bsums);
    k_scan2<<<1, 64, 0, stream>>>(bsums, bscan);
    k_scan3<<<SCAN_NB, 1024, 0, stream>>>(deg, bscan, offs, cursor);
    k_compose<<<258, 128, 0, stream>>>(W_emb, b_emb, Wl1, bl1, Wr1,
                                       Wl1f, bl1f, Wr1f, br1f, zerob);
    k_packwe<<<16, 256, 0, stream>>>(We1, We2, Wepk1, Wepk2);

    // fat dispatch: layer-1 lin (composed weights, input x) + CSR scatter
    k_fat1<<<LINB + SCATB, 256, 0, stream>>>(x, Wl1f, bl1f, Wr1f, br1f, xl, xr,
                                             ei, flag, cursor, e_src, ea, ea_h);

    int fuse_grid = (HIP_N + 1) / 2;   // 2 nodes per 128-thread block
    // ----- layer 1 -----
    k_node_fused<<<fuse_grid, 128, 0, stream>>>(offs, e_src, ea_h, Wepk1, att1,
                                                xl, xr, bo1, h);
    // ----- layer 2 -----
    k_lin<<<(HIP_N + 31) / 32, 256, 0, stream>>>(h, Wl2, bl2, Wr2, zerob, xl, xr, HIP_N);
    k_node_fused<<<fuse_grid, 128, 0, stream>>>(offs, e_src, ea_h, Wepk2, att2,
                                                xl, xr, bo2, out);
}

// Round 15
// 496.480 us; speedup vs baseline: 1.0222x; 1.0222x over previous
//
#include <hip/hip_runtime.h>
#include <hip/hip_bf16.h>
#include <math.h>

// HelicalGNNFrontend: 2-layer GATv2 (heads=1, self-loops, mean loop edge_attr)
// N=50000, E=800000, NODE_DIM=HID=128, EDGE_DIM=32.
//
// Round 15: R13 fused config restored (1-wave workgroups — R14's 2-node pack
// gained no occupancy and added imbalance). New: xl/xr stored as packed
// half2 (f16): halves the per-edge gather bytes (512->256B), lin write
// traffic, and prefetch VGPRs. lin epilogue pairs lanes via shfl_down +
// cvt_pkrtz; fused converts h2->f32 on use (2 cvt/edge).
// Keep: f16 fdot2 eproj, exp2-domain logits, fmax leaky, fat1 overlap,
// composed layer-1 weights, hierarchical scan, self-loop-last, defer-max.

#define HIP_N 50000
#define HIP_E 800000
#define HIP_H 128
#define HIP_ED 32
#define NEG_SLOPE 0.2f
#define RESCALE_THR_LOG2 11.5416f   // 8 / ln2
#define LINB ((HIP_N + 31) / 32)          // 1563 lin blocks
#define SCATB ((HIP_E + 255) / 256)       // 3125 scatter blocks
#define INV_LN2 1.4426950408889634f

typedef __fp16 h2 __attribute__((ext_vector_type(2)));

__device__ __forceinline__ h2 u2h(unsigned int u) {
    union { unsigned int u; h2 h; } c; c.u = u; return c.h;
}
__device__ __forceinline__ unsigned int pkh(float a, float b) {
    union { h2 h; unsigned int u; } c;
    c.h = __builtin_amdgcn_cvt_pkrtz(a, b);
    return c.u;
}
__device__ __forceinline__ float2 h2f(unsigned int u) {
    h2 h = u2h(u);
    return make_float2((float)h.x, (float)h.y);
}

// ---------------- edge-index dtype detection ----------------
__global__ void k_detect(const int* __restrict__ ei, int* __restrict__ is32) {
    int j = blockIdx.x * blockDim.x + threadIdx.x;   // j in [0, 4096)
    if (j < 4096) {
        if (ei[2 * j + 1] != 0) atomicOr(is32, 1);
    }
}

__device__ __forceinline__ int fetch_idx(const int* __restrict__ ei, int is32, long long pos) {
    return is32 ? ei[pos] : ei[2 * pos];  // little-endian low word for int64
}

// ---------------- CSR build ----------------
__global__ void k_hist(const int* __restrict__ ei, const int* __restrict__ flag,
                       int* __restrict__ deg) {
    int is32 = *flag;
    int e = blockIdx.x * blockDim.x + threadIdx.x;
    if (e < HIP_E) {
        int d = fetch_idx(ei, is32, (long long)HIP_E + e);
        atomicAdd(&deg[d], 1);
    }
}

#define SCAN_TILE 1024
#define SCAN_NB ((HIP_N + SCAN_TILE - 1) / SCAN_TILE)   // 49

__global__ __launch_bounds__(256) void k_scan1(const int* __restrict__ deg,
                                               int* __restrict__ bsums) {
    __shared__ int ws[4];
    int b = blockIdx.x, t = threadIdx.x;
    int base = b * SCAN_TILE;
    int v = 0;
#pragma unroll
    for (int j = 0; j < 4; ++j) {
        int i = base + t + 256 * j;
        if (i < HIP_N) v += deg[i];
    }
#pragma unroll
    for (int off = 32; off > 0; off >>= 1) v += __shfl_xor(v, off);
    int lane = t & 63, wid = t >> 6;
    if (lane == 0) ws[wid] = v;
    __syncthreads();
    if (t == 0) bsums[b] = ws[0] + ws[1] + ws[2] + ws[3];
}

__global__ __launch_bounds__(64) void k_scan2(const int* __restrict__ bsums,
                                              int* __restrict__ bscan) {
    int t = threadIdx.x;
    int v = (t < SCAN_NB) ? bsums[t] : 0;
    int incl = v;
#pragma unroll
    for (int off = 1; off < 64; off <<= 1) {
        int u = __shfl_up(incl, off);
        if (t >= off) incl += u;
    }
    if (t < SCAN_NB) bscan[t] = incl - v;   // exclusive
}

__global__ __launch_bounds__(1024) void k_scan3(const int* __restrict__ deg,
                                                const int* __restrict__ bscan,
                                                int* __restrict__ offs,
                                                int* __restrict__ cursor) {
    __shared__ int wsum[16];
    int b = blockIdx.x, t = threadIdx.x;
    int i = b * SCAN_TILE + t;
    int lane = t & 63, wid = t >> 6;
    int v = (i < HIP_N) ? deg[i] : 0;
    int incl = v;
#pragma unroll
    for (int off = 1; off < 64; off <<= 1) {
        int u = __shfl_up(incl, off);
        if (lane >= off) incl += u;
    }
    if (lane == 63) wsum[wid] = incl;
    __syncthreads();
    if (wid == 0 && lane < 16) {
        int w = wsum[lane];
#pragma unroll
        for (int off = 1; off < 16; off <<= 1) {
            int u = __shfl_up(w, off);
            if (lane >= off) w += u;
        }
        wsum[lane] = w;   // inclusive over waves
    }
    __syncthreads();
    int baseadd = bscan[b] + (wid > 0 ? wsum[wid - 1] : 0);
    int excl = baseadd + incl - v;
    if (i < HIP_N) {
        offs[i] = excl;
        cursor[i] = excl;
        if (i == HIP_N - 1) offs[HIP_N] = excl + v;
    }
}

// ---------------- shared bodies ----------------
// dual GEMM body; outputs packed half2 (even lanes pair with odd neighbor)
__device__ __forceinline__ void lin_body(const float* __restrict__ h,
                                         const float* __restrict__ Wl,
                                         const float* __restrict__ bl,
                                         const float* __restrict__ Wr,
                                         const float* __restrict__ br,
                                         unsigned int* __restrict__ xlh,
                                         unsigned int* __restrict__ xrh,
                                         int n, int blk) {
    __shared__ float tile[32][128];
    int rb = blk * 32;
    int tid = threadIdx.x;
    for (int j = 0; j < 16; ++j) {
        int idx = j * 256 + tid;
        int r = idx >> 7, c = idx & 127;
        int row = rb + r;
        tile[r][c] = (row < n) ? h[(size_t)row * 128 + c] : 0.f;
    }
    __syncthreads();
    int c = tid & 127, g = tid >> 7;
    float accl[16], accr[16];
#pragma unroll
    for (int r = 0; r < 16; ++r) { accl[r] = 0.f; accr[r] = 0.f; }
    for (int d4 = 0; d4 < 32; ++d4) {
        int d = d4 * 4;
        float wl0 = Wl[(d + 0) * 128 + c];
        float wl1 = Wl[(d + 1) * 128 + c];
        float wl2 = Wl[(d + 2) * 128 + c];
        float wl3 = Wl[(d + 3) * 128 + c];
        float wr0 = Wr[(d + 0) * 128 + c];
        float wr1 = Wr[(d + 1) * 128 + c];
        float wr2 = Wr[(d + 2) * 128 + c];
        float wr3 = Wr[(d + 3) * 128 + c];
#pragma unroll
        for (int r = 0; r < 16; ++r) {
            const float4 hv = *(const float4*)&tile[g * 16 + r][d];
            accl[r] += hv.x * wl0 + hv.y * wl1 + hv.z * wl2 + hv.w * wl3;
            accr[r] += hv.x * wr0 + hv.y * wr1 + hv.z * wr2 + hv.w * wr3;
        }
    }
    float bbl = bl[c], bbr = br[c];
    bool evenc = !(c & 1);
#pragma unroll
    for (int r = 0; r < 16; ++r) {
        int row = rb + g * 16 + r;
        float vl = accl[r] + bbl;
        float vr = accr[r] + bbr;
        float vl1 = __shfl_down(vl, 1);     // odd neighbor's value
        float vr1 = __shfl_down(vr, 1);
        if (evenc && row < n) {
            xlh[(size_t)row * 64 + (c >> 1)] = pkh(vl, vl1);
            xrh[(size_t)row * 64 + (c >> 1)] = pkh(vr, vr1);
        }
    }
}

// scatter body: e_src[pos]=src, ea_h[pos]= half2-packed ea row (64B)
__device__ __forceinline__ void scatter_body(const int* __restrict__ ei, int is32,
                                             int* __restrict__ cursor,
                                             int* __restrict__ e_src,
                                             const float* __restrict__ ea,
                                             unsigned int* __restrict__ ea_h, int e) {
    if (e < HIP_E) {
        int s = fetch_idx(ei, is32, e);
        int d = fetch_idx(ei, is32, (long long)HIP_E + e);
        int pos = atomicAdd(&cursor[d], 1);
        e_src[pos] = s;
        const float4* src4 = (const float4*)(ea + (size_t)e * HIP_ED);
        float4 s0 = src4[0], s1 = src4[1], s2 = src4[2], s3 = src4[3];
        float4 s4 = src4[4], s5 = src4[5], s6 = src4[6], s7 = src4[7];
        uint4* dst = (uint4*)(ea_h + (size_t)pos * 16);
        dst[0] = make_uint4(pkh(s0.x, s0.y), pkh(s0.z, s0.w),
                            pkh(s1.x, s1.y), pkh(s1.z, s1.w));
        dst[1] = make_uint4(pkh(s2.x, s2.y), pkh(s2.z, s2.w),
                            pkh(s3.x, s3.y), pkh(s3.z, s3.w));
        dst[2] = make_uint4(pkh(s4.x, s4.y), pkh(s4.z, s4.w),
                            pkh(s5.x, s5.y), pkh(s5.z, s5.w));
        dst[3] = make_uint4(pkh(s6.x, s6.y), pkh(s6.z, s6.w),
                            pkh(s7.x, s7.y), pkh(s7.z, s7.w));
    }
}

// fat kernel: blocks [0, LINB) do layer-1 lin; blocks [LINB, LINB+SCATB) scatter
__global__ __launch_bounds__(256) void k_fat1(
    const float* __restrict__ x, const float* __restrict__ Wl,
    const float* __restrict__ bl, const float* __restrict__ Wr,
    const float* __restrict__ br,
    unsigned int* __restrict__ xlh, unsigned int* __restrict__ xrh,
    const int* __restrict__ ei, const int* __restrict__ flag,
    int* __restrict__ cursor, int* __restrict__ e_src,
    const float* __restrict__ ea, unsigned int* __restrict__ ea_h) {
    if (blockIdx.x < LINB) {
        lin_body(x, Wl, bl, Wr, br, xlh, xrh, HIP_N, blockIdx.x);
    } else {
        int e = (blockIdx.x - LINB) * 256 + threadIdx.x;
        scatter_body(ei, *flag, cursor, e_src, ea, ea_h, e);
    }
}

__global__ __launch_bounds__(256) void k_lin(const float* __restrict__ h,
                                             const float* __restrict__ Wl,
                                             const float* __restrict__ bl,
                                             const float* __restrict__ Wr,
                                             const float* __restrict__ br,
                                             unsigned int* __restrict__ xlh,
                                             unsigned int* __restrict__ xrh, int n) {
    lin_body(h, Wl, bl, Wr, br, xlh, xrh, n, blockIdx.x);
}

// ---------------- weight composition (folds k_emb into layer-1) ----------------
__global__ __launch_bounds__(128) void k_compose(
    const float* __restrict__ Wemb, const float* __restrict__ bemb,
    const float* __restrict__ Wl, const float* __restrict__ bl,
    const float* __restrict__ Wr,
    float* __restrict__ Wlf, float* __restrict__ blf,
    float* __restrict__ Wrf, float* __restrict__ brf,
    float* __restrict__ zerob) {
    int b = blockIdx.x, c = threadIdx.x;
    if (b < 128) {
        float acc = 0.f;
        for (int k = 0; k < 128; ++k) acc += Wemb[b * 128 + k] * Wl[k * 128 + c];
        Wlf[b * 128 + c] = acc;
    } else if (b < 256) {
        int r = b - 128;
        float acc = 0.f;
        for (int k = 0; k < 128; ++k) acc += Wemb[r * 128 + k] * Wr[k * 128 + c];
        Wrf[r * 128 + c] = acc;
    } else if (b == 256) {
        float acc = bl[c];
        for (int k = 0; k < 128; ++k) acc += bemb[k] * Wl[k * 128 + c];
        blf[c] = acc;
    } else {
        float acc = 0.f;
        for (int k = 0; k < 128; ++k) acc += bemb[k] * Wr[k * 128 + c];
        brf[c] = acc;
        zerob[c] = 0.f;
    }
}

// pack We (32x128 fp32) -> Wepk (2048 uint: half2 over d-pairs)
// Wepk[d2*128 + j*64 + t] = half2(We[2*d2][2*t+j], We[2*d2+1][2*t+j])
__global__ __launch_bounds__(256) void k_packwe(const float* __restrict__ We1,
                                                const float* __restrict__ We2,
                                                unsigned int* __restrict__ P1,
                                                unsigned int* __restrict__ P2) {
    int idx = blockIdx.x * 256 + threadIdx.x;     // [0, 4096)
    if (idx < 4096) {
        const float* We = (idx < 2048) ? We1 : We2;
        unsigned int* P = (idx < 2048) ? P1 : P2;
        int r = idx & 2047;
        int d2 = r >> 7, rem = r & 127;
        int j = rem >> 6, t = rem & 63;
        int col = 2 * t + j;
        P[r] = pkh(We[(2 * d2) * 128 + col], We[(2 * d2 + 1) * 128 + col]);
    }
}

// ---------------- fused per-node online softmax + aggregation ----------------
// ONE 64-thread block per node. Per-edge addresses wave-uniform -> s_load;
// only the xl gather (now ONE dword: half2) on vector memory. eproj: 32x
// fdot2. Logits in exp2 domain. 2-wide edge pipeline.
__global__ __launch_bounds__(64) void k_node_fused(
    const int* __restrict__ offs, const int* __restrict__ e_src,
    const unsigned int* __restrict__ ea_h,
    const unsigned int* __restrict__ Wepk, const float* __restrict__ att,
    const unsigned int* __restrict__ xlh, const unsigned int* __restrict__ xrh,
    const float* __restrict__ bo, float* __restrict__ hout) {
    int i = blockIdx.x;           // uniform node id
    int t = threadIdx.x;          // lane, owns feature dims (2t, 2t+1)

    // We pairs: wxK = (We[2K][2t], We[2K+1][2t]), wyK = same for dim 2t+1
    h2 wx00 = u2h(Wepk[ 0*128 + t]),      wy00 = u2h(Wepk[ 0*128 + 64 + t]);
    h2 wx01 = u2h(Wepk[ 1*128 + t]),      wy01 = u2h(Wepk[ 1*128 + 64 + t]);
    h2 wx02 = u2h(Wepk[ 2*128 + t]),      wy02 = u2h(Wepk[ 2*128 + 64 + t]);
    h2 wx03 = u2h(Wepk[ 3*128 + t]),      wy03 = u2h(Wepk[ 3*128 + 64 + t]);
    h2 wx04 = u2h(Wepk[ 4*128 + t]),      wy04 = u2h(Wepk[ 4*128 + 64 + t]);
    h2 wx05 = u2h(Wepk[ 5*128 + t]),      wy05 = u2h(Wepk[ 5*128 + 64 + t]);
    h2 wx06 = u2h(Wepk[ 6*128 + t]),      wy06 = u2h(Wepk[ 6*128 + 64 + t]);
    h2 wx07 = u2h(Wepk[ 7*128 + t]),      wy07 = u2h(Wepk[ 7*128 + 64 + t]);
    h2 wx08 = u2h(Wepk[ 8*128 + t]),      wy08 = u2h(Wepk[ 8*128 + 64 + t]);
    h2 wx09 = u2h(Wepk[ 9*128 + t]),      wy09 = u2h(Wepk[ 9*128 + 64 + t]);
    h2 wx10 = u2h(Wepk[10*128 + t]),      wy10 = u2h(Wepk[10*128 + 64 + t]);
    h2 wx11 = u2h(Wepk[11*128 + t]),      wy11 = u2h(Wepk[11*128 + 64 + t]);
    h2 wx12 = u2h(Wepk[12*128 + t]),      wy12 = u2h(Wepk[12*128 + 64 + t]);
    h2 wx13 = u2h(Wepk[13*128 + t]),      wy13 = u2h(Wepk[13*128 + 64 + t]);
    h2 wx14 = u2h(Wepk[14*128 + t]),      wy14 = u2h(Wepk[14*128 + 64 + t]);
    h2 wx15 = u2h(Wepk[15*128 + t]),      wy15 = u2h(Wepk[15*128 + 64 + t]);

    float2 attv = ((const float2*)att)[t];
    attv.x *= INV_LN2; attv.y *= INV_LN2;   // exp2-domain logits
    float2 bov  = ((const float2*)bo)[t];
    float2 xri  = h2f(xrh[(size_t)i * 64 + t]);
    float2 xli  = h2f(xlh[(size_t)i * 64 + t]);

    float m = -1e30f;
    float denom = 0.f;
    float accx = 0.f, accy = 0.f;
    float epsx = 0.f, epsy = 0.f;   // sum of per-edge eproj (for self-loop)

    int o0 = offs[i], o1 = offs[i + 1];     // uniform -> s_load
    int cnt = o1 - o0;
    int pairs = cnt >> 1;

#define DOTP(EX, EY, U, K)                                            \
    EX = __builtin_amdgcn_fdot2(u2h(U), wx##K, EX, false);            \
    EY = __builtin_amdgcn_fdot2(u2h(U), wy##K, EY, false);

#define EPROJ(EX, EY, P)                                              \
    {                                                                 \
        uint4 q0 = ((const uint4*)(P))[0];                            \
        uint4 q1 = ((const uint4*)(P))[1];                            \
        uint4 q2 = ((const uint4*)(P))[2];                            \
        uint4 q3 = ((const uint4*)(P))[3];                            \
        DOTP(EX, EY, q0.x, 00) DOTP(EX, EY, q0.y, 01)                 \
        DOTP(EX, EY, q0.z, 02) DOTP(EX, EY, q0.w, 03)                 \
        DOTP(EX, EY, q1.x, 04) DOTP(EX, EY, q1.y, 05)                 \
        DOTP(EX, EY, q1.z, 06) DOTP(EX, EY, q1.w, 07)                 \
        DOTP(EX, EY, q2.x, 08) DOTP(EX, EY, q2.y, 09)                 \
        DOTP(EX, EY, q2.z, 10) DOTP(EX, EY, q2.w, 11)                 \
        DOTP(EX, EY, q3.x, 12) DOTP(EX, EY, q3.y, 13)                 \
        DOTP(EX, EY, q3.z, 14) DOTP(EX, EY, q3.w, 15)                 \
    }

    // pair-ahead prefetch of the two xl gathers (one dword each)
    unsigned int uA = 0, uB = 0;
    if (pairs > 0) {
        int s0 = e_src[o0];                 // uniform -> s_load
        int s1 = e_src[o0 + 1];
        uA = xlh[(size_t)s0 * 64 + t];
        uB = xlh[(size_t)s1 * 64 + t];
    }

    for (int pp = 0; pp < pairs; ++pp) {
        int e = o0 + 2 * pp;
        float2 x0 = h2f(uA), x1 = h2f(uB);
        if (pp + 1 < pairs) {               // prefetch next pair's gathers
            int s0 = e_src[e + 2];
            int s1 = e_src[e + 3];
            uA = xlh[(size_t)s0 * 64 + t];
            uB = xlh[(size_t)s1 * 64 + t];
        }
        const unsigned int* er = ea_h + (size_t)e * 16;   // uniform (2 rows, 32 dw)
        float ex0 = 0.f, ey0 = 0.f, ex1 = 0.f, ey1 = 0.f;
        EPROJ(ex0, ey0, er)
        EPROJ(ex1, ey1, er + 16)
        epsx += ex0 + ex1; epsy += ey0 + ey1;
        float vx0 = x0.x + xri.x + ex0, vy0 = x0.y + xri.y + ey0;
        float vx1 = x1.x + xri.x + ex1, vy1 = x1.y + xri.y + ey1;
        vx0 = fmaxf(vx0, NEG_SLOPE * vx0);   // leaky_relu as single max
        vy0 = fmaxf(vy0, NEG_SLOPE * vy0);
        vx1 = fmaxf(vx1, NEG_SLOPE * vx1);
        vy1 = fmaxf(vy1, NEG_SLOPE * vy1);
        float p0 = vx0 * attv.x + vy0 * attv.y;
        float p1 = vx1 * attv.x + vy1 * attv.y;
#pragma unroll
        for (int off = 32; off > 0; off >>= 1) {   // interleaved chains
            p0 += __shfl_xor(p0, off);
            p1 += __shfl_xor(p1, off);
        }
        float pm = fmaxf(p0, p1);
        if (pm > m + RESCALE_THR_LOG2) {    // defer-max rescale (wave-uniform)
            float sc = exp2f(m - pm);
            accx *= sc; accy *= sc; denom *= sc;
            m = pm;
        }
        float wA = exp2f(p0 - m);
        float wB = exp2f(p1 - m);
        accx += wA * x0.x + wB * x1.x;
        accy += wA * x0.y + wB * x1.y;
        denom += wA + wB;
    }

    if (cnt & 1) {                          // tail edge
        int e = o1 - 1;
        int s = e_src[e];
        float2 x0 = h2f(xlh[(size_t)s * 64 + t]);
        const unsigned int* er = ea_h + (size_t)e * 16;
        float ex = 0.f, ey = 0.f;
        EPROJ(ex, ey, er)
        epsx += ex; epsy += ey;
        float vx = x0.x + xri.x + ex;
        float vy = x0.y + xri.y + ey;
        vx = fmaxf(vx, NEG_SLOPE * vx);
        vy = fmaxf(vy, NEG_SLOPE * vy);
        float p = vx * attv.x + vy * attv.y;
#pragma unroll
        for (int off = 32; off > 0; off >>= 1) p += __shfl_xor(p, off);
        if (p > m + RESCALE_THR_LOG2) {
            float sc = exp2f(m - p);
            accx *= sc; accy *= sc; denom *= sc;
            m = p;
        }
        float w = exp2f(p - m);
        accx += w * x0.x;
        accy += w * x0.y;
        denom += w;
    }
#undef EPROJ
#undef DOTP

    // ---- self-loop (last): loop_attr projection = mean of eproj ----
    float invdeg = 1.f / fmaxf((float)cnt, 1.f);
    float sx = xli.x + xri.x + epsx * invdeg;
    float sy = xli.y + xri.y + epsy * invdeg;
    sx = fmaxf(sx, NEG_SLOPE * sx);
    sy = fmaxf(sy, NEG_SLOPE * sy);
    float ps = sx * attv.x + sy * attv.y;
#pragma unroll
    for (int off = 32; off > 0; off >>= 1) ps += __shfl_xor(ps, off);

    float mm = fmaxf(m, ps);
    float wf = exp2f(m - mm);
    float ws = exp2f(ps - mm);
    denom = denom * wf + ws;
    accx = accx * wf + ws * xli.x;
    accy = accy * wf + ws * xli.y;

    float ox = accx / denom + bov.x;
    float oy = accy / denom + bov.y;
    float2 o;
    o.x = ox / (1.f + __expf(-ox));
    o.y = oy / (1.f + __expf(-oy));
    ((float2*)(hout + (size_t)i * HIP_H))[t] = o;
}

// ---------------- host launch ----------------
extern "C" void kernel_launch(void* const* d_in, const int* in_sizes, int n_in,
                              void* d_out, int out_size, void* d_ws, size_t ws_size,
                              hipStream_t stream) {
    const float* x      = (const float*)d_in[0];
    const int*   ei     = (const int*)d_in[1];
    const float* ea     = (const float*)d_in[2];
    const float* W_emb  = (const float*)d_in[3];
    const float* b_emb  = (const float*)d_in[4];
    const float* Wl1    = (const float*)d_in[5];
    const float* bl1    = (const float*)d_in[6];
    const float* Wr1    = (const float*)d_in[7];
    const float* We1    = (const float*)d_in[8];
    const float* att1   = (const float*)d_in[9];
    const float* bo1    = (const float*)d_in[10];
    const float* Wl2    = (const float*)d_in[11];
    const float* bl2    = (const float*)d_in[12];
    const float* Wr2    = (const float*)d_in[13];
    const float* We2    = (const float*)d_in[14];
    const float* att2   = (const float*)d_in[15];
    const float* bo2    = (const float*)d_in[16];
    float* out = (float*)d_out;

    char* p = (char*)d_ws;
    auto carve = [&](size_t bytes) {
        void* q = (void*)p;
        p += (bytes + 255) / 256 * 256;
        return q;
    };
    float* h        = (float*)carve((size_t)HIP_N * 128 * 4);
    unsigned int* xlh = (unsigned int*)carve((size_t)HIP_N * 64 * 4);
    unsigned int* xrh = (unsigned int*)carve((size_t)HIP_N * 64 * 4);
    unsigned int* ea_h = (unsigned int*)carve((size_t)HIP_E * 16 * 4);
    int*   deg      = (int*)carve((size_t)HIP_N * 4);
    int*   offs     = (int*)carve((size_t)(HIP_N + 1) * 4);
    int*   cursor   = (int*)carve((size_t)HIP_N * 4);
    int*   e_src    = (int*)carve((size_t)HIP_E * 4);
    int*   flag     = (int*)carve(256);
    int*   bsums    = (int*)carve((size_t)SCAN_NB * 4);
    int*   bscan    = (int*)carve((size_t)SCAN_NB * 4);
    float* Wl1f     = (float*)carve(128 * 128 * 4);
    float* Wr1f     = (float*)carve(128 * 128 * 4);
    float* bl1f     = (float*)carve(128 * 4);
    float* br1f     = (float*)carve(128 * 4);
    float* zerob    = (float*)carve(128 * 4);
    unsigned int* Wepk1 = (unsigned int*)carve(2048 * 4);
    unsigned int* Wepk2 = (unsigned int*)carve(2048 * 4);

    hipMemsetAsync(deg, 0, (size_t)HIP_N * 4, stream);
    hipMemsetAsync(flag, 0, 4, stream);

    k_detect<<<16, 256, 0, stream>>>(ei, flag);
    k_hist<<<(HIP_E + 255) / 256, 256, 0, stream>>>(ei, flag, deg);
    k_scan1<<<SCAN_NB, 256, 0, stream>>>(deg, bsums);
    k_scan2<<<1, 64, 0, stream>>>(bsums, bscan);
    k_scan3<<<SCAN_NB, 1024, 0, stream>>>(deg, bscan, offs, cursor);
    k_compose<<<258, 128, 0, stream>>>(W_emb, b_emb, Wl1, bl1, Wr1,
                                       Wl1f, bl1f, Wr1f, br1f, zerob);
    k_packwe<<<16, 256, 0, stream>>>(We1, We2, Wepk1, Wepk2);

    // fat dispatch: layer-1 lin (composed weights, input x) + CSR scatter
    k_fat1<<<LINB + SCATB, 256, 0, stream>>>(x, Wl1f, bl1f, Wr1f, br1f, xlh, xrh,
                                             ei, flag, cursor, e_src, ea, ea_h);

    // ----- layer 1 -----
    k_node_fused<<<HIP_N, 64, 0, stream>>>(offs, e_src, ea_h, Wepk1, att1,
                                           xlh, xrh, bo1, h);
    // ----- layer 2 -----
    k_lin<<<(HIP_N + 31) / 32, 256, 0, stream>>>(h, Wl2, bl2, Wr2, zerob, xlh, xrh, HIP_N);
    k_node_fused<<<HIP_N, 64, 0, stream>>>(offs, e_src, ea_h, Wepk2, att2,
                                           xlh, xrh, bo2, out);
}

// Round 16
// 452.155 us; speedup vs baseline: 1.1224x; 1.0980x over previous
//
#include <hip/hip_runtime.h>
#include <hip/hip_bf16.h>
#include <math.h>

// HelicalGNNFrontend: 2-layer GATv2 (heads=1, self-loops, mean loop edge_attr)
// N=50000, E=800000, NODE_DIM=HID=128, EDGE_DIM=32.
//
// Round 16: MFMA the two dual-GEMMs (xl|xr = h @ [Wl|Wr]) with
// v_mfma_f32_16x16x32_f16: M=50k (3125x16 tiles), N=256, K=128, f16 in /
// fp32 acc. Weights pre-transposed+packed f16 [N][K] (k_packw); A converted
// fp32->f16 in-register; C packed to half2 xl/xr via even-lane pkh+shfl.
// Fused kernel frozen at R15 (f16 xl/xr, fdot2 eproj, exp2 logits, 2-wide
// pipeline, scalar s_load edge stream). fat1 = MFMA-lin1 + scatter overlap.

#define HIP_N 50000
#define HIP_E 800000
#define HIP_H 128
#define HIP_ED 32
#define NEG_SLOPE 0.2f
#define RESCALE_THR_LOG2 11.5416f   // 8 / ln2
#define LINM 3125                   // 50000 / 16 M-tiles
#define SCATB ((HIP_E + 255) / 256) // 3125 scatter blocks
#define INV_LN2 1.4426950408889634f

typedef __fp16 h2 __attribute__((ext_vector_type(2)));
typedef _Float16 half8 __attribute__((ext_vector_type(8)));
typedef float f32x4 __attribute__((ext_vector_type(4)));

__device__ __forceinline__ h2 u2h(unsigned int u) {
    union { unsigned int u; h2 h; } c; c.u = u; return c.h;
}
__device__ __forceinline__ unsigned int pkh(float a, float b) {
    union { h2 h; unsigned int u; } c;
    c.h = __builtin_amdgcn_cvt_pkrtz(a, b);
    return c.u;
}
__device__ __forceinline__ float2 h2f(unsigned int u) {
    h2 h = u2h(u);
    return make_float2((float)h.x, (float)h.y);
}
__device__ __forceinline__ half8 u4h8(uint4 u) {
    union { uint4 u; half8 h; } c; c.u = u; return c.h;
}

// ---------------- edge-index dtype detection ----------------
__global__ void k_detect(const int* __restrict__ ei, int* __restrict__ is32) {
    int j = blockIdx.x * blockDim.x + threadIdx.x;   // j in [0, 4096)
    if (j < 4096) {
        if (ei[2 * j + 1] != 0) atomicOr(is32, 1);
    }
}

__device__ __forceinline__ int fetch_idx(const int* __restrict__ ei, int is32, long long pos) {
    return is32 ? ei[pos] : ei[2 * pos];  // little-endian low word for int64
}

// ---------------- CSR build ----------------
__global__ void k_hist(const int* __restrict__ ei, const int* __restrict__ flag,
                       int* __restrict__ deg) {
    int is32 = *flag;
    int e = blockIdx.x * blockDim.x + threadIdx.x;
    if (e < HIP_E) {
        int d = fetch_idx(ei, is32, (long long)HIP_E + e);
        atomicAdd(&deg[d], 1);
    }
}

#define SCAN_TILE 1024
#define SCAN_NB ((HIP_N + SCAN_TILE - 1) / SCAN_TILE)   // 49

__global__ __launch_bounds__(256) void k_scan1(const int* __restrict__ deg,
                                               int* __restrict__ bsums) {
    __shared__ int ws[4];
    int b = blockIdx.x, t = threadIdx.x;
    int base = b * SCAN_TILE;
    int v = 0;
#pragma unroll
    for (int j = 0; j < 4; ++j) {
        int i = base + t + 256 * j;
        if (i < HIP_N) v += deg[i];
    }
#pragma unroll
    for (int off = 32; off > 0; off >>= 1) v += __shfl_xor(v, off);
    int lane = t & 63, wid = t >> 6;
    if (lane == 0) ws[wid] = v;
    __syncthreads();
    if (t == 0) bsums[b] = ws[0] + ws[1] + ws[2] + ws[3];
}

__global__ __launch_bounds__(64) void k_scan2(const int* __restrict__ bsums,
                                              int* __restrict__ bscan) {
    int t = threadIdx.x;
    int v = (t < SCAN_NB) ? bsums[t] : 0;
    int incl = v;
#pragma unroll
    for (int off = 1; off < 64; off <<= 1) {
        int u = __shfl_up(incl, off);
        if (t >= off) incl += u;
    }
    if (t < SCAN_NB) bscan[t] = incl - v;   // exclusive
}

__global__ __launch_bounds__(1024) void k_scan3(const int* __restrict__ deg,
                                                const int* __restrict__ bscan,
                                                int* __restrict__ offs,
                                                int* __restrict__ cursor) {
    __shared__ int wsum[16];
    int b = blockIdx.x, t = threadIdx.x;
    int i = b * SCAN_TILE + t;
    int lane = t & 63, wid = t >> 6;
    int v = (i < HIP_N) ? deg[i] : 0;
    int incl = v;
#pragma unroll
    for (int off = 1; off < 64; off <<= 1) {
        int u = __shfl_up(incl, off);
        if (lane >= off) incl += u;
    }
    if (lane == 63) wsum[wid] = incl;
    __syncthreads();
    if (wid == 0 && lane < 16) {
        int w = wsum[lane];
#pragma unroll
        for (int off = 1; off < 16; off <<= 1) {
            int u = __shfl_up(w, off);
            if (lane >= off) w += u;
        }
        wsum[lane] = w;   // inclusive over waves
    }
    __syncthreads();
    int baseadd = bscan[b] + (wid > 0 ? wsum[wid - 1] : 0);
    int excl = baseadd + incl - v;
    if (i < HIP_N) {
        offs[i] = excl;
        cursor[i] = excl;
        if (i == HIP_N - 1) offs[HIP_N] = excl + v;
    }
}

// ---------------- MFMA dual-GEMM body ----------------
// out[xl|xr] = A[50k,128] @ Wt^T (Wt stored [256][128] f16) + bias[256]
// Block: 256 threads = 4 waves; wave w covers N = w*64..w*64+63; M-tile = blk.
__device__ __forceinline__ void linm_body(const float* __restrict__ A,
                                          const unsigned short* __restrict__ Wt,
                                          const float* __restrict__ bias,
                                          unsigned int* __restrict__ xlh,
                                          unsigned int* __restrict__ xrh, int blk) {
    int tid = threadIdx.x;
    int wid = tid >> 6, l = tid & 63;
    int li = l & 15, lk = l >> 4;          // A row / C col = li; k-group = lk
    size_t arow = (size_t)(blk * 16 + li) * 128;

    f32x4 acc0 = {0.f, 0.f, 0.f, 0.f};
    f32x4 acc1 = {0.f, 0.f, 0.f, 0.f};
    f32x4 acc2 = {0.f, 0.f, 0.f, 0.f};
    f32x4 acc3 = {0.f, 0.f, 0.f, 0.f};

#pragma unroll
    for (int ks = 0; ks < 4; ++ks) {
        int kb = ks * 32 + lk * 8;
        const float4* ap = (const float4*)(A + arow + kb);
        float4 a0 = ap[0], a1 = ap[1];
        half8 afrag = u4h8(make_uint4(pkh(a0.x, a0.y), pkh(a0.z, a0.w),
                                      pkh(a1.x, a1.y), pkh(a1.z, a1.w)));
        int nbase = wid * 64 + li;
        half8 b0 = u4h8(*(const uint4*)(Wt + (size_t)(nbase +  0) * 128 + kb));
        half8 b1 = u4h8(*(const uint4*)(Wt + (size_t)(nbase + 16) * 128 + kb));
        half8 b2 = u4h8(*(const uint4*)(Wt + (size_t)(nbase + 32) * 128 + kb));
        half8 b3 = u4h8(*(const uint4*)(Wt + (size_t)(nbase + 48) * 128 + kb));
        acc0 = __builtin_amdgcn_mfma_f32_16x16x32_f16(afrag, b0, acc0, 0, 0, 0);
        acc1 = __builtin_amdgcn_mfma_f32_16x16x32_f16(afrag, b1, acc1, 0, 0, 0);
        acc2 = __builtin_amdgcn_mfma_f32_16x16x32_f16(afrag, b2, acc2, 0, 0, 0);
        acc3 = __builtin_amdgcn_mfma_f32_16x16x32_f16(afrag, b3, acc3, 0, 0, 0);
    }

    // epilogue: C col = li, row = lk*4 + r; pack col pairs via even lanes
    bool even = !(l & 1);
#pragma unroll
    for (int nt = 0; nt < 4; ++nt) {
        f32x4 a = (nt == 0) ? acc0 : (nt == 1) ? acc1 : (nt == 2) ? acc2 : acc3;
        int n = wid * 64 + nt * 16 + li;
        float bb = bias[n];
        unsigned int* outp = (n < 128) ? xlh : xrh;
        int nn = n & 127;
#pragma unroll
        for (int r = 0; r < 4; ++r) {
            int rowg = blk * 16 + lk * 4 + r;
            float v = a[r] + bb;
            float v1 = __shfl_down(v, 1);
            if (even) outp[(size_t)rowg * 64 + (nn >> 1)] = pkh(v, v1);
        }
    }
}

// scatter body: e_src[pos]=src, ea_h[pos]= half2-packed ea row (64B)
__device__ __forceinline__ void scatter_body(const int* __restrict__ ei, int is32,
                                             int* __restrict__ cursor,
                                             int* __restrict__ e_src,
                                             const float* __restrict__ ea,
                                             unsigned int* __restrict__ ea_h, int e) {
    if (e < HIP_E) {
        int s = fetch_idx(ei, is32, e);
        int d = fetch_idx(ei, is32, (long long)HIP_E + e);
        int pos = atomicAdd(&cursor[d], 1);
        e_src[pos] = s;
        const float4* src4 = (const float4*)(ea + (size_t)e * HIP_ED);
        float4 s0 = src4[0], s1 = src4[1], s2 = src4[2], s3 = src4[3];
        float4 s4 = src4[4], s5 = src4[5], s6 = src4[6], s7 = src4[7];
        uint4* dst = (uint4*)(ea_h + (size_t)pos * 16);
        dst[0] = make_uint4(pkh(s0.x, s0.y), pkh(s0.z, s0.w),
                            pkh(s1.x, s1.y), pkh(s1.z, s1.w));
        dst[1] = make_uint4(pkh(s2.x, s2.y), pkh(s2.z, s2.w),
                            pkh(s3.x, s3.y), pkh(s3.z, s3.w));
        dst[2] = make_uint4(pkh(s4.x, s4.y), pkh(s4.z, s4.w),
                            pkh(s5.x, s5.y), pkh(s5.z, s5.w));
        dst[3] = make_uint4(pkh(s6.x, s6.y), pkh(s6.z, s6.w),
                            pkh(s7.x, s7.y), pkh(s7.z, s7.w));
    }
}

// fat kernel: blocks [0, LINM) do layer-1 MFMA lin; rest scatter
__global__ __launch_bounds__(256) void k_fat1(
    const float* __restrict__ x, const unsigned short* __restrict__ Wt1,
    const float* __restrict__ b1,
    unsigned int* __restrict__ xlh, unsigned int* __restrict__ xrh,
    const int* __restrict__ ei, const int* __restrict__ flag,
    int* __restrict__ cursor, int* __restrict__ e_src,
    const float* __restrict__ ea, unsigned int* __restrict__ ea_h) {
    if (blockIdx.x < LINM) {
        linm_body(x, Wt1, b1, xlh, xrh, blockIdx.x);
    } else {
        int e = (blockIdx.x - LINM) * 256 + threadIdx.x;
        scatter_body(ei, *flag, cursor, e_src, ea, ea_h, e);
    }
}

__global__ __launch_bounds__(256) void k_linm(const float* __restrict__ A,
                                              const unsigned short* __restrict__ Wt,
                                              const float* __restrict__ bias,
                                              unsigned int* __restrict__ xlh,
                                              unsigned int* __restrict__ xrh) {
    linm_body(A, Wt, bias, xlh, xrh, blockIdx.x);
}

// ---------------- weight composition (folds k_emb into layer-1) ----------------
__global__ __launch_bounds__(128) void k_compose(
    const float* __restrict__ Wemb, const float* __restrict__ bemb,
    const float* __restrict__ Wl, const float* __restrict__ bl,
    const float* __restrict__ Wr,
    float* __restrict__ Wlf, float* __restrict__ blf,
    float* __restrict__ Wrf, float* __restrict__ brf) {
    int b = blockIdx.x, c = threadIdx.x;
    if (b < 128) {
        float acc = 0.f;
        for (int k = 0; k < 128; ++k) acc += Wemb[b * 128 + k] * Wl[k * 128 + c];
        Wlf[b * 128 + c] = acc;
    } else if (b < 256) {
        int r = b - 128;
        float acc = 0.f;
        for (int k = 0; k < 128; ++k) acc += Wemb[r * 128 + k] * Wr[k * 128 + c];
        Wrf[r * 128 + c] = acc;
    } else if (b == 256) {
        float acc = bl[c];
        for (int k = 0; k < 128; ++k) acc += bemb[k] * Wl[k * 128 + c];
        blf[c] = acc;
    } else {
        float acc = 0.f;
        for (int k = 0; k < 128; ++k) acc += bemb[k] * Wr[k * 128 + c];
        brf[c] = acc;
    }
}

// pack transposed f16 weights [N=256][K=128] + bias[256] for both layers
// grid 512 blocks x 128 threads: block = layer*256 + n; thread = k
__global__ __launch_bounds__(128) void k_packw(
    const float* __restrict__ Wl1f, const float* __restrict__ Wr1f,
    const float* __restrict__ bl1f, const float* __restrict__ br1f,
    const float* __restrict__ Wl2, const float* __restrict__ bl2,
    const float* __restrict__ Wr2,
    unsigned short* __restrict__ Wt1, unsigned short* __restrict__ Wt2,
    float* __restrict__ b1, float* __restrict__ b2) {
    int b = blockIdx.x, k = threadIdx.x;
    int layer = b >> 8, n = b & 255;
    int nn = n & 127;
    const float* W;
    if (layer == 0) W = (n < 128) ? Wl1f : Wr1f;
    else            W = (n < 128) ? Wl2 : Wr2;
    float v = W[k * 128 + nn];
    union { __fp16 h; unsigned short s; } cv;
    cv.h = (__fp16)v;
    (layer ? Wt2 : Wt1)[(size_t)n * 128 + k] = cv.s;
    if (k == 0) {
        float bv;
        if (layer == 0) bv = (n < 128) ? bl1f[nn] : br1f[nn];
        else            bv = (n < 128) ? bl2[nn] : 0.f;
        (layer ? b2 : b1)[n] = bv;
    }
}

// pack We (32x128 fp32) -> Wepk (2048 uint: half2 over d-pairs)
__global__ __launch_bounds__(256) void k_packwe(const float* __restrict__ We1,
                                                const float* __restrict__ We2,
                                                unsigned int* __restrict__ P1,
                                                unsigned int* __restrict__ P2) {
    int idx = blockIdx.x * 256 + threadIdx.x;     // [0, 4096)
    if (idx < 4096) {
        const float* We = (idx < 2048) ? We1 : We2;
        unsigned int* P = (idx < 2048) ? P1 : P2;
        int r = idx & 2047;
        int d2 = r >> 7, rem = r & 127;
        int j = rem >> 6, t = rem & 63;
        int col = 2 * t + j;
        P[r] = pkh(We[(2 * d2) * 128 + col], We[(2 * d2 + 1) * 128 + col]);
    }
}

// ---------------- fused per-node online softmax + aggregation ----------------
// (frozen from R15) ONE 64-thread block per node; scalar s_load edge stream;
// f16 packed xl/xr gathers; 32x fdot2 eproj; exp2 logits; 2-wide pipeline.
__global__ __launch_bounds__(64) void k_node_fused(
    const int* __restrict__ offs, const int* __restrict__ e_src,
    const unsigned int* __restrict__ ea_h,
    const unsigned int* __restrict__ Wepk, const float* __restrict__ att,
    const unsigned int* __restrict__ xlh, const unsigned int* __restrict__ xrh,
    const float* __restrict__ bo, float* __restrict__ hout) {
    int i = blockIdx.x;           // uniform node id
    int t = threadIdx.x;          // lane, owns feature dims (2t, 2t+1)

    h2 wx00 = u2h(Wepk[ 0*128 + t]),      wy00 = u2h(Wepk[ 0*128 + 64 + t]);
    h2 wx01 = u2h(Wepk[ 1*128 + t]),      wy01 = u2h(Wepk[ 1*128 + 64 + t]);
    h2 wx02 = u2h(Wepk[ 2*128 + t]),      wy02 = u2h(Wepk[ 2*128 + 64 + t]);
    h2 wx03 = u2h(Wepk[ 3*128 + t]),      wy03 = u2h(Wepk[ 3*128 + 64 + t]);
    h2 wx04 = u2h(Wepk[ 4*128 + t]),      wy04 = u2h(Wepk[ 4*128 + 64 + t]);
    h2 wx05 = u2h(Wepk[ 5*128 + t]),      wy05 = u2h(Wepk[ 5*128 + 64 + t]);
    h2 wx06 = u2h(Wepk[ 6*128 + t]),      wy06 = u2h(Wepk[ 6*128 + 64 + t]);
    h2 wx07 = u2h(Wepk[ 7*128 + t]),      wy07 = u2h(Wepk[ 7*128 + 64 + t]);
    h2 wx08 = u2h(Wepk[ 8*128 + t]),      wy08 = u2h(Wepk[ 8*128 + 64 + t]);
    h2 wx09 = u2h(Wepk[ 9*128 + t]),      wy09 = u2h(Wepk[ 9*128 + 64 + t]);
    h2 wx10 = u2h(Wepk[10*128 + t]),      wy10 = u2h(Wepk[10*128 + 64 + t]);
    h2 wx11 = u2h(Wepk[11*128 + t]),      wy11 = u2h(Wepk[11*128 + 64 + t]);
    h2 wx12 = u2h(Wepk[12*128 + t]),      wy12 = u2h(Wepk[12*128 + 64 + t]);
    h2 wx13 = u2h(Wepk[13*128 + t]),      wy13 = u2h(Wepk[13*128 + 64 + t]);
    h2 wx14 = u2h(Wepk[14*128 + t]),      wy14 = u2h(Wepk[14*128 + 64 + t]);
    h2 wx15 = u2h(Wepk[15*128 + t]),      wy15 = u2h(Wepk[15*128 + 64 + t]);

    float2 attv = ((const float2*)att)[t];
    attv.x *= INV_LN2; attv.y *= INV_LN2;   // exp2-domain logits
    float2 bov  = ((const float2*)bo)[t];
    float2 xri  = h2f(xrh[(size_t)i * 64 + t]);
    float2 xli  = h2f(xlh[(size_t)i * 64 + t]);

    float m = -1e30f;
    float denom = 0.f;
    float accx = 0.f, accy = 0.f;
    float epsx = 0.f, epsy = 0.f;   // sum of per-edge eproj (for self-loop)

    int o0 = offs[i], o1 = offs[i + 1];     // uniform -> s_load
    int cnt = o1 - o0;
    int pairs = cnt >> 1;

#define DOTP(EX, EY, U, K)                                            \
    EX = __builtin_amdgcn_fdot2(u2h(U), wx##K, EX, false);            \
    EY = __builtin_amdgcn_fdot2(u2h(U), wy##K, EY, false);

#define EPROJ(EX, EY, P)                                              \
    {                                                                 \
        uint4 q0 = ((const uint4*)(P))[0];                            \
        uint4 q1 = ((const uint4*)(P))[1];                            \
        uint4 q2 = ((const uint4*)(P))[2];                            \
        uint4 q3 = ((const uint4*)(P))[3];                            \
        DOTP(EX, EY, q0.x, 00) DOTP(EX, EY, q0.y, 01)                 \
        DOTP(EX, EY, q0.z, 02) DOTP(EX, EY, q0.w, 03)                 \
        DOTP(EX, EY, q1.x, 04) DOTP(EX, EY, q1.y, 05)                 \
        DOTP(EX, EY, q1.z, 06) DOTP(EX, EY, q1.w, 07)                 \
        DOTP(EX, EY, q2.x, 08) DOTP(EX, EY, q2.y, 09)                 \
        DOTP(EX, EY, q2.z, 10) DOTP(EX, EY, q2.w, 11)                 \
        DOTP(EX, EY, q3.x, 12) DOTP(EX, EY, q3.y, 13)                 \
        DOTP(EX, EY, q3.z, 14) DOTP(EX, EY, q3.w, 15)                 \
    }

    unsigned int uA = 0, uB = 0;
    if (pairs > 0) {
        int s0 = e_src[o0];                 // uniform -> s_load
        int s1 = e_src[o0 + 1];
        uA = xlh[(size_t)s0 * 64 + t];
        uB = xlh[(size_t)s1 * 64 + t];
    }

    for (int pp = 0; pp < pairs; ++pp) {
        int e = o0 + 2 * pp;
        float2 x0 = h2f(uA), x1 = h2f(uB);
        if (pp + 1 < pairs) {               // prefetch next pair's gathers
            int s0 = e_src[e + 2];
            int s1 = e_src[e + 3];
            uA = xlh[(size_t)s0 * 64 + t];
            uB = xlh[(size_t)s1 * 64 + t];
        }
        const unsigned int* er = ea_h + (size_t)e * 16;   // uniform
        float ex0 = 0.f, ey0 = 0.f, ex1 = 0.f, ey1 = 0.f;
        EPROJ(ex0, ey0, er)
        EPROJ(ex1, ey1, er + 16)
        epsx += ex0 + ex1; epsy += ey0 + ey1;
        float vx0 = x0.x + xri.x + ex0, vy0 = x0.y + xri.y + ey0;
        float vx1 = x1.x + xri.x + ex1, vy1 = x1.y + xri.y + ey1;
        vx0 = fmaxf(vx0, NEG_SLOPE * vx0);
        vy0 = fmaxf(vy0, NEG_SLOPE * vy0);
        vx1 = fmaxf(vx1, NEG_SLOPE * vx1);
        vy1 = fmaxf(vy1, NEG_SLOPE * vy1);
        float p0 = vx0 * attv.x + vy0 * attv.y;
        float p1 = vx1 * attv.x + vy1 * attv.y;
#pragma unroll
        for (int off = 32; off > 0; off >>= 1) {
            p0 += __shfl_xor(p0, off);
            p1 += __shfl_xor(p1, off);
        }
        float pm = fmaxf(p0, p1);
        if (pm > m + RESCALE_THR_LOG2) {
            float sc = exp2f(m - pm);
            accx *= sc; accy *= sc; denom *= sc;
            m = pm;
        }
        float wA = exp2f(p0 - m);
        float wB = exp2f(p1 - m);
        accx += wA * x0.x + wB * x1.x;
        accy += wA * x0.y + wB * x1.y;
        denom += wA + wB;
    }

    if (cnt & 1) {                          // tail edge
        int e = o1 - 1;
        int s = e_src[e];
        float2 x0 = h2f(xlh[(size_t)s * 64 + t]);
        const unsigned int* er = ea_h + (size_t)e * 16;
        float ex = 0.f, ey = 0.f;
        EPROJ(ex, ey, er)
        epsx += ex; epsy += ey;
        float vx = x0.x + xri.x + ex;
        float vy = x0.y + xri.y + ey;
        vx = fmaxf(vx, NEG_SLOPE * vx);
        vy = fmaxf(vy, NEG_SLOPE * vy);
        float p = vx * attv.x + vy * attv.y;
#pragma unroll
        for (int off = 32; off > 0; off >>= 1) p += __shfl_xor(p, off);
        if (p > m + RESCALE_THR_LOG2) {
            float sc = exp2f(m - p);
            accx *= sc; accy *= sc; denom *= sc;
            m = p;
        }
        float w = exp2f(p - m);
        accx += w * x0.x;
        accy += w * x0.y;
        denom += w;
    }
#undef EPROJ
#undef DOTP

    // ---- self-loop (last): loop_attr projection = mean of eproj ----
    float invdeg = 1.f / fmaxf((float)cnt, 1.f);
    float sx = xli.x + xri.x + epsx * invdeg;
    float sy = xli.y + xri.y + epsy * invdeg;
    sx = fmaxf(sx, NEG_SLOPE * sx);
    sy = fmaxf(sy, NEG_SLOPE * sy);
    float ps = sx * attv.x + sy * attv.y;
#pragma unroll
    for (int off = 32; off > 0; off >>= 1) ps += __shfl_xor(ps, off);

    float mm = fmaxf(m, ps);
    float wf = exp2f(m - mm);
    float ws = exp2f(ps - mm);
    denom = denom * wf + ws;
    accx = accx * wf + ws * xli.x;
    accy = accy * wf + ws * xli.y;

    float ox = accx / denom + bov.x;
    float oy = accy / denom + bov.y;
    float2 o;
    o.x = ox / (1.f + __expf(-ox));
    o.y = oy / (1.f + __expf(-oy));
    ((float2*)(hout + (size_t)i * HIP_H))[t] = o;
}

// ---------------- host launch ----------------
extern "C" void kernel_launch(void* const* d_in, const int* in_sizes, int n_in,
                              void* d_out, int out_size, void* d_ws, size_t ws_size,
                              hipStream_t stream) {
    const float* x      = (const float*)d_in[0];
    const int*   ei     = (const int*)d_in[1];
    const float* ea     = (const float*)d_in[2];
    const float* W_emb  = (const float*)d_in[3];
    const float* b_emb  = (const float*)d_in[4];
    const float* Wl1    = (const float*)d_in[5];
    const float* bl1    = (const float*)d_in[6];
    const float* Wr1    = (const float*)d_in[7];
    const float* We1    = (const float*)d_in[8];
    const float* att1   = (const float*)d_in[9];
    const float* bo1    = (const float*)d_in[10];
    const float* Wl2    = (const float*)d_in[11];
    const float* bl2    = (const float*)d_in[12];
    const float* Wr2    = (const float*)d_in[13];
    const float* We2    = (const float*)d_in[14];
    const float* att2   = (const float*)d_in[15];
    const float* bo2    = (const float*)d_in[16];
    float* out = (float*)d_out;

    char* p = (char*)d_ws;
    auto carve = [&](size_t bytes) {
        void* q = (void*)p;
        p += (bytes + 255) / 256 * 256;
        return q;
    };
    float* h        = (float*)carve((size_t)HIP_N * 128 * 4);
    unsigned int* xlh = (unsigned int*)carve((size_t)HIP_N * 64 * 4);
    unsigned int* xrh = (unsigned int*)carve((size_t)HIP_N * 64 * 4);
    unsigned int* ea_h = (unsigned int*)carve((size_t)HIP_E * 16 * 4);
    int*   deg      = (int*)carve((size_t)HIP_N * 4);
    int*   offs     = (int*)carve((size_t)(HIP_N + 1) * 4);
    int*   cursor   = (int*)carve((size_t)HIP_N * 4);
    int*   e_src    = (int*)carve((size_t)HIP_E * 4);
    int*   flag     = (int*)carve(256);
    int*   bsums    = (int*)carve((size_t)SCAN_NB * 4);
    int*   bscan    = (int*)carve((size_t)SCAN_NB * 4);
    float* Wl1f     = (float*)carve(128 * 128 * 4);
    float* Wr1f     = (float*)carve(128 * 128 * 4);
    float* bl1f     = (float*)carve(128 * 4);
    float* br1f     = (float*)carve(128 * 4);
    unsigned int* Wepk1 = (unsigned int*)carve(2048 * 4);
    unsigned int* Wepk2 = (unsigned int*)carve(2048 * 4);
    unsigned short* Wt1 = (unsigned short*)carve(256 * 128 * 2);
    unsigned short* Wt2 = (unsigned short*)carve(256 * 128 * 2);
    float* b1       = (float*)carve(256 * 4);
    float* b2       = (float*)carve(256 * 4);

    hipMemsetAsync(deg, 0, (size_t)HIP_N * 4, stream);
    hipMemsetAsync(flag, 0, 4, stream);

    k_detect<<<16, 256, 0, stream>>>(ei, flag);
    k_hist<<<(HIP_E + 255) / 256, 256, 0, stream>>>(ei, flag, deg);
    k_scan1<<<SCAN_NB, 256, 0, stream>>>(deg, bsums);
    k_scan2<<<1, 64, 0, stream>>>(bsums, bscan);
    k_scan3<<<SCAN_NB, 1024, 0, stream>>>(deg, bscan, offs, cursor);
    k_compose<<<258, 128, 0, stream>>>(W_emb, b_emb, Wl1, bl1, Wr1,
                                       Wl1f, bl1f, Wr1f, br1f);
    k_packwe<<<16, 256, 0, stream>>>(We1, We2, Wepk1, Wepk2);
    k_packw<<<512, 128, 0, stream>>>(Wl1f, Wr1f, bl1f, br1f, Wl2, bl2, Wr2,
                                     Wt1, Wt2, b1, b2);

    // fat dispatch: layer-1 MFMA lin (composed weights, input x) + CSR scatter
    k_fat1<<<LINM + SCATB, 256, 0, stream>>>(x, Wt1, b1, xlh, xrh,
                                             ei, flag, cursor, e_src, ea, ea_h);

    // ----- layer 1 -----
    k_node_fused<<<HIP_N, 64, 0, stream>>>(offs, e_src, ea_h, Wepk1, att1,
                                           xlh, xrh, bo1, h);
    // ----- layer 2 -----
    k_linm<<<LINM, 256, 0, stream>>>(h, Wt2, b2, xlh, xrh);
    k_node_fused<<<HIP_N, 64, 0, stream>>>(offs, e_src, ea_h, Wepk2, att2,
                                           xlh, xrh, bo2, out);
}

// Round 17
// 443.426 us; speedup vs baseline: 1.1445x; 1.0197x over previous
//
#include <hip/hip_runtime.h>
#include <hip/hip_bf16.h>
#include <math.h>

// HelicalGNNFrontend: 2-layer GATv2 (heads=1, self-loops, mean loop edge_attr)
// N=50000, E=800000, NODE_DIM=HID=128, EDGE_DIM=32.
//
// Round 17: dispatch-count reduction (15 -> 10 graph nodes). All
// preprocessing fused into ONE k_prep (compose->Wt1 direct transposed-f16,
// layer-2 transpose, biases, We pack, edge-dtype detect, deg zeroing);
// scan2 folded into scan3 (per-block masked wave reduce of 49 bsums).
// Compute kernels frozen from R16: MFMA dual-GEMM (fat1/linm), fused
// per-node online softmax (f16 fdot2, scalar edge stream, 2-wide pipeline).

#define HIP_N 50000
#define HIP_E 800000
#define HIP_H 128
#define HIP_ED 32
#define NEG_SLOPE 0.2f
#define RESCALE_THR_LOG2 11.5416f   // 8 / ln2
#define LINM 3125                   // 50000 / 16 M-tiles
#define SCATB ((HIP_E + 255) / 256) // 3125 scatter blocks
#define INV_LN2 1.4426950408889634f

typedef __fp16 h2 __attribute__((ext_vector_type(2)));
typedef _Float16 half8 __attribute__((ext_vector_type(8)));
typedef float f32x4 __attribute__((ext_vector_type(4)));

__device__ __forceinline__ h2 u2h(unsigned int u) {
    union { unsigned int u; h2 h; } c; c.u = u; return c.h;
}
__device__ __forceinline__ unsigned int pkh(float a, float b) {
    union { h2 h; unsigned int u; } c;
    c.h = __builtin_amdgcn_cvt_pkrtz(a, b);
    return c.u;
}
__device__ __forceinline__ float2 h2f(unsigned int u) {
    h2 h = u2h(u);
    return make_float2((float)h.x, (float)h.y);
}
__device__ __forceinline__ half8 u4h8(uint4 u) {
    union { uint4 u; half8 h; } c; c.u = u; return c.h;
}

__device__ __forceinline__ int fetch_idx(const int* __restrict__ ei, int is32, long long pos) {
    return is32 ? ei[pos] : ei[2 * pos];  // little-endian low word for int64
}

// ---------------- mega prep kernel (128 threads/block) ----------------
// blocks [0,256): compose W_emb@{Wl1,Wr1} row -> Wt1 transposed f16
// blocks 256,257: layer-1 biases (b_emb@W + b)
// blocks 258,259: layer-2 biases (bl2, 0)
// blocks [260,388): layer-2 weight transpose -> Wt2 f16
// blocks [388,420): We1/We2 pack -> Wepk1/2
// blocks [420,452): edge-index dtype detect (4096 odd words)
// blocks [452,843): zero deg
#define PREP_NB (452 + (HIP_N + 127) / 128)

__global__ __launch_bounds__(128) void k_prep(
    const float* __restrict__ Wemb, const float* __restrict__ bemb,
    const float* __restrict__ Wl1, const float* __restrict__ bl1,
    const float* __restrict__ Wr1,
    const float* __restrict__ Wl2, const float* __restrict__ bl2,
    const float* __restrict__ Wr2,
    const float* __restrict__ We1, const float* __restrict__ We2,
    const int* __restrict__ ei, int* __restrict__ flag,
    unsigned short* __restrict__ Wt1, unsigned short* __restrict__ Wt2,
    float* __restrict__ b1, float* __restrict__ b2,
    unsigned int* __restrict__ Wepk1, unsigned int* __restrict__ Wepk2,
    int* __restrict__ deg) {
    int b = blockIdx.x, t = threadIdx.x;
    if (b < 256) {
        int r = b & 127;
        const float* W = (b < 128) ? Wl1 : Wr1;
        int nofs = (b < 128) ? 0 : 128;
        float acc = 0.f;
        for (int k = 0; k < 128; ++k) acc += Wemb[r * 128 + k] * W[k * 128 + t];
        union { __fp16 h; unsigned short s; } cv;
        cv.h = (__fp16)acc;
        Wt1[(size_t)(nofs + t) * 128 + r] = cv.s;   // Wt1[n][k] = Wf[k][n]
    } else if (b == 256) {
        float acc = bl1[t];
        for (int k = 0; k < 128; ++k) acc += bemb[k] * Wl1[k * 128 + t];
        b1[t] = acc;
    } else if (b == 257) {
        float acc = 0.f;
        for (int k = 0; k < 128; ++k) acc += bemb[k] * Wr1[k * 128 + t];
        b1[128 + t] = acc;
    } else if (b == 258) {
        b2[t] = bl2[t];
    } else if (b == 259) {
        b2[128 + t] = 0.f;
    } else if (b < 388) {
        int k = b - 260;                            // row of Wl2/Wr2
        float vl = Wl2[k * 128 + t], vr = Wr2[k * 128 + t];
        union { __fp16 h; unsigned short s; } c1, c2;
        c1.h = (__fp16)vl; c2.h = (__fp16)vr;
        Wt2[(size_t)t * 128 + k] = c1.s;
        Wt2[(size_t)(128 + t) * 128 + k] = c2.s;
    } else if (b < 420) {
        int idx = (b - 388) * 128 + t;              // [0, 4096)
        const float* We = (idx < 2048) ? We1 : We2;
        unsigned int* P = (idx < 2048) ? Wepk1 : Wepk2;
        int r = idx & 2047;
        int d2 = r >> 7, rem = r & 127;
        int j = rem >> 6, tt = rem & 63;
        int col = 2 * tt + j;
        P[r] = pkh(We[(2 * d2) * 128 + col], We[(2 * d2 + 1) * 128 + col]);
    } else if (b < 452) {
        int j = (b - 420) * 128 + t;                // [0, 4096)
        if (ei[2 * j + 1] != 0) atomicOr(flag, 1);
    } else {
        int i = (b - 452) * 128 + t;
        if (i < HIP_N) deg[i] = 0;
    }
}

// ---------------- CSR build ----------------
__global__ void k_hist(const int* __restrict__ ei, const int* __restrict__ flag,
                       int* __restrict__ deg) {
    int is32 = *flag;
    int e = blockIdx.x * blockDim.x + threadIdx.x;
    if (e < HIP_E) {
        int d = fetch_idx(ei, is32, (long long)HIP_E + e);
        atomicAdd(&deg[d], 1);
    }
}

#define SCAN_TILE 1024
#define SCAN_NB ((HIP_N + SCAN_TILE - 1) / SCAN_TILE)   // 49

__global__ __launch_bounds__(256) void k_scan1(const int* __restrict__ deg,
                                               int* __restrict__ bsums) {
    __shared__ int ws[4];
    int b = blockIdx.x, t = threadIdx.x;
    int base = b * SCAN_TILE;
    int v = 0;
#pragma unroll
    for (int j = 0; j < 4; ++j) {
        int i = base + t + 256 * j;
        if (i < HIP_N) v += deg[i];
    }
#pragma unroll
    for (int off = 32; off > 0; off >>= 1) v += __shfl_xor(v, off);
    int lane = t & 63, wid = t >> 6;
    if (lane == 0) ws[wid] = v;
    __syncthreads();
    if (t == 0) bsums[b] = ws[0] + ws[1] + ws[2] + ws[3];
}

// scan3 with folded scan2: block computes its own bsums prefix
__global__ __launch_bounds__(1024) void k_scan3(const int* __restrict__ deg,
                                                const int* __restrict__ bsums,
                                                int* __restrict__ offs,
                                                int* __restrict__ cursor) {
    __shared__ int wsum[16];
    __shared__ int bbase_sh;
    int b = blockIdx.x, t = threadIdx.x;
    int i = b * SCAN_TILE + t;
    int lane = t & 63, wid = t >> 6;
    if (wid == 0) {                      // prefix of bsums[0..b-1] via masked reduce
        int v = (lane < SCAN_NB && lane < b) ? bsums[lane] : 0;
#pragma unroll
        for (int off = 32; off > 0; off >>= 1) v += __shfl_xor(v, off);
        if (lane == 0) bbase_sh = v;
    }
    int v = (i < HIP_N) ? deg[i] : 0;
    int incl = v;
#pragma unroll
    for (int off = 1; off < 64; off <<= 1) {
        int u = __shfl_up(incl, off);
        if (lane >= off) incl += u;
    }
    if (lane == 63) wsum[wid] = incl;
    __syncthreads();
    if (wid == 0 && lane < 16) {
        int w = wsum[lane];
#pragma unroll
        for (int off = 1; off < 16; off <<= 1) {
            int u = __shfl_up(w, off);
            if (lane >= off) w += u;
        }
        wsum[lane] = w;   // inclusive over waves
    }
    __syncthreads();
    int baseadd = bbase_sh + (wid > 0 ? wsum[wid - 1] : 0);
    int excl = baseadd + incl - v;
    if (i < HIP_N) {
        offs[i] = excl;
        cursor[i] = excl;
        if (i == HIP_N - 1) offs[HIP_N] = excl + v;
    }
}

// ---------------- MFMA dual-GEMM body ----------------
__device__ __forceinline__ void linm_body(const float* __restrict__ A,
                                          const unsigned short* __restrict__ Wt,
                                          const float* __restrict__ bias,
                                          unsigned int* __restrict__ xlh,
                                          unsigned int* __restrict__ xrh, int blk) {
    int tid = threadIdx.x;
    int wid = tid >> 6, l = tid & 63;
    int li = l & 15, lk = l >> 4;          // A row / C col = li; k-group = lk
    size_t arow = (size_t)(blk * 16 + li) * 128;

    f32x4 acc0 = {0.f, 0.f, 0.f, 0.f};
    f32x4 acc1 = {0.f, 0.f, 0.f, 0.f};
    f32x4 acc2 = {0.f, 0.f, 0.f, 0.f};
    f32x4 acc3 = {0.f, 0.f, 0.f, 0.f};

#pragma unroll
    for (int ks = 0; ks < 4; ++ks) {
        int kb = ks * 32 + lk * 8;
        const float4* ap = (const float4*)(A + arow + kb);
        float4 a0 = ap[0], a1 = ap[1];
        half8 afrag = u4h8(make_uint4(pkh(a0.x, a0.y), pkh(a0.z, a0.w),
                                      pkh(a1.x, a1.y), pkh(a1.z, a1.w)));
        int nbase = wid * 64 + li;
        half8 b0 = u4h8(*(const uint4*)(Wt + (size_t)(nbase +  0) * 128 + kb));
        half8 b1 = u4h8(*(const uint4*)(Wt + (size_t)(nbase + 16) * 128 + kb));
        half8 b2 = u4h8(*(const uint4*)(Wt + (size_t)(nbase + 32) * 128 + kb));
        half8 b3 = u4h8(*(const uint4*)(Wt + (size_t)(nbase + 48) * 128 + kb));
        acc0 = __builtin_amdgcn_mfma_f32_16x16x32_f16(afrag, b0, acc0, 0, 0, 0);
        acc1 = __builtin_amdgcn_mfma_f32_16x16x32_f16(afrag, b1, acc1, 0, 0, 0);
        acc2 = __builtin_amdgcn_mfma_f32_16x16x32_f16(afrag, b2, acc2, 0, 0, 0);
        acc3 = __builtin_amdgcn_mfma_f32_16x16x32_f16(afrag, b3, acc3, 0, 0, 0);
    }

    bool even = !(l & 1);
#pragma unroll
    for (int nt = 0; nt < 4; ++nt) {
        f32x4 a = (nt == 0) ? acc0 : (nt == 1) ? acc1 : (nt == 2) ? acc2 : acc3;
        int n = wid * 64 + nt * 16 + li;
        float bb = bias[n];
        unsigned int* outp = (n < 128) ? xlh : xrh;
        int nn = n & 127;
#pragma unroll
        for (int r = 0; r < 4; ++r) {
            int rowg = blk * 16 + lk * 4 + r;
            float v = a[r] + bb;
            float v1 = __shfl_down(v, 1);
            if (even) outp[(size_t)rowg * 64 + (nn >> 1)] = pkh(v, v1);
        }
    }
}

// scatter body: e_src[pos]=src, ea_h[pos]= half2-packed ea row (64B)
__device__ __forceinline__ void scatter_body(const int* __restrict__ ei, int is32,
                                             int* __restrict__ cursor,
                                             int* __restrict__ e_src,
                                             const float* __restrict__ ea,
                                             unsigned int* __restrict__ ea_h, int e) {
    if (e < HIP_E) {
        int s = fetch_idx(ei, is32, e);
        int d = fetch_idx(ei, is32, (long long)HIP_E + e);
        int pos = atomicAdd(&cursor[d], 1);
        e_src[pos] = s;
        const float4* src4 = (const float4*)(ea + (size_t)e * HIP_ED);
        float4 s0 = src4[0], s1 = src4[1], s2 = src4[2], s3 = src4[3];
        float4 s4 = src4[4], s5 = src4[5], s6 = src4[6], s7 = src4[7];
        uint4* dst = (uint4*)(ea_h + (size_t)pos * 16);
        dst[0] = make_uint4(pkh(s0.x, s0.y), pkh(s0.z, s0.w),
                            pkh(s1.x, s1.y), pkh(s1.z, s1.w));
        dst[1] = make_uint4(pkh(s2.x, s2.y), pkh(s2.z, s2.w),
                            pkh(s3.x, s3.y), pkh(s3.z, s3.w));
        dst[2] = make_uint4(pkh(s4.x, s4.y), pkh(s4.z, s4.w),
                            pkh(s5.x, s5.y), pkh(s5.z, s5.w));
        dst[3] = make_uint4(pkh(s6.x, s6.y), pkh(s6.z, s6.w),
                            pkh(s7.x, s7.y), pkh(s7.z, s7.w));
    }
}

// fat kernel: blocks [0, LINM) do layer-1 MFMA lin; rest scatter
__global__ __launch_bounds__(256) void k_fat1(
    const float* __restrict__ x, const unsigned short* __restrict__ Wt1,
    const float* __restrict__ b1,
    unsigned int* __restrict__ xlh, unsigned int* __restrict__ xrh,
    const int* __restrict__ ei, const int* __restrict__ flag,
    int* __restrict__ cursor, int* __restrict__ e_src,
    const float* __restrict__ ea, unsigned int* __restrict__ ea_h) {
    if (blockIdx.x < LINM) {
        linm_body(x, Wt1, b1, xlh, xrh, blockIdx.x);
    } else {
        int e = (blockIdx.x - LINM) * 256 + threadIdx.x;
        scatter_body(ei, *flag, cursor, e_src, ea, ea_h, e);
    }
}

__global__ __launch_bounds__(256) void k_linm(const float* __restrict__ A,
                                              const unsigned short* __restrict__ Wt,
                                              const float* __restrict__ bias,
                                              unsigned int* __restrict__ xlh,
                                              unsigned int* __restrict__ xrh) {
    linm_body(A, Wt, bias, xlh, xrh, blockIdx.x);
}

// ---------------- fused per-node online softmax + aggregation ----------------
// (frozen from R15/R16) ONE 64-thread block per node; scalar s_load edge
// stream; f16 packed xl/xr gathers; 32x fdot2 eproj; exp2 logits; 2-wide.
__global__ __launch_bounds__(64) void k_node_fused(
    const int* __restrict__ offs, const int* __restrict__ e_src,
    const unsigned int* __restrict__ ea_h,
    const unsigned int* __restrict__ Wepk, const float* __restrict__ att,
    const unsigned int* __restrict__ xlh, const unsigned int* __restrict__ xrh,
    const float* __restrict__ bo, float* __restrict__ hout) {
    int i = blockIdx.x;           // uniform node id
    int t = threadIdx.x;          // lane, owns feature dims (2t, 2t+1)

    h2 wx00 = u2h(Wepk[ 0*128 + t]),      wy00 = u2h(Wepk[ 0*128 + 64 + t]);
    h2 wx01 = u2h(Wepk[ 1*128 + t]),      wy01 = u2h(Wepk[ 1*128 + 64 + t]);
    h2 wx02 = u2h(Wepk[ 2*128 + t]),      wy02 = u2h(Wepk[ 2*128 + 64 + t]);
    h2 wx03 = u2h(Wepk[ 3*128 + t]),      wy03 = u2h(Wepk[ 3*128 + 64 + t]);
    h2 wx04 = u2h(Wepk[ 4*128 + t]),      wy04 = u2h(Wepk[ 4*128 + 64 + t]);
    h2 wx05 = u2h(Wepk[ 5*128 + t]),      wy05 = u2h(Wepk[ 5*128 + 64 + t]);
    h2 wx06 = u2h(Wepk[ 6*128 + t]),      wy06 = u2h(Wepk[ 6*128 + 64 + t]);
    h2 wx07 = u2h(Wepk[ 7*128 + t]),      wy07 = u2h(Wepk[ 7*128 + 64 + t]);
    h2 wx08 = u2h(Wepk[ 8*128 + t]),      wy08 = u2h(Wepk[ 8*128 + 64 + t]);
    h2 wx09 = u2h(Wepk[ 9*128 + t]),      wy09 = u2h(Wepk[ 9*128 + 64 + t]);
    h2 wx10 = u2h(Wepk[10*128 + t]),      wy10 = u2h(Wepk[10*128 + 64 + t]);
    h2 wx11 = u2h(Wepk[11*128 + t]),      wy11 = u2h(Wepk[11*128 + 64 + t]);
    h2 wx12 = u2h(Wepk[12*128 + t]),      wy12 = u2h(Wepk[12*128 + 64 + t]);
    h2 wx13 = u2h(Wepk[13*128 + t]),      wy13 = u2h(Wepk[13*128 + 64 + t]);
    h2 wx14 = u2h(Wepk[14*128 + t]),      wy14 = u2h(Wepk[14*128 + 64 + t]);
    h2 wx15 = u2h(Wepk[15*128 + t]),      wy15 = u2h(Wepk[15*128 + 64 + t]);

    float2 attv = ((const float2*)att)[t];
    attv.x *= INV_LN2; attv.y *= INV_LN2;   // exp2-domain logits
    float2 bov  = ((const float2*)bo)[t];
    float2 xri  = h2f(xrh[(size_t)i * 64 + t]);
    float2 xli  = h2f(xlh[(size_t)i * 64 + t]);

    float m = -1e30f;
    float denom = 0.f;
    float accx = 0.f, accy = 0.f;
    float epsx = 0.f, epsy = 0.f;   // sum of per-edge eproj (for self-loop)

    int o0 = offs[i], o1 = offs[i + 1];     // uniform -> s_load
    int cnt = o1 - o0;
    int pairs = cnt >> 1;

#define DOTP(EX, EY, U, K)                                            \
    EX = __builtin_amdgcn_fdot2(u2h(U), wx##K, EX, false);            \
    EY = __builtin_amdgcn_fdot2(u2h(U), wy##K, EY, false);

#define EPROJ(EX, EY, P)                                              \
    {                                                                 \
        uint4 q0 = ((const uint4*)(P))[0];                            \
        uint4 q1 = ((const uint4*)(P))[1];                            \
        uint4 q2 = ((const uint4*)(P))[2];                            \
        uint4 q3 = ((const uint4*)(P))[3];                            \
        DOTP(EX, EY, q0.x, 00) DOTP(EX, EY, q0.y, 01)                 \
        DOTP(EX, EY, q0.z, 02) DOTP(EX, EY, q0.w, 03)                 \
        DOTP(EX, EY, q1.x, 04) DOTP(EX, EY, q1.y, 05)                 \
        DOTP(EX, EY, q1.z, 06) DOTP(EX, EY, q1.w, 07)                 \
        DOTP(EX, EY, q2.x, 08) DOTP(EX, EY, q2.y, 09)                 \
        DOTP(EX, EY, q2.z, 10) DOTP(EX, EY, q2.w, 11)                 \
        DOTP(EX, EY, q3.x, 12) DOTP(EX, EY, q3.y, 13)                 \
        DOTP(EX, EY, q3.z, 14) DOTP(EX, EY, q3.w, 15)                 \
    }

    unsigned int uA = 0, uB = 0;
    if (pairs > 0) {
        int s0 = e_src[o0];                 // uniform -> s_load
        int s1 = e_src[o0 + 1];
        uA = xlh[(size_t)s0 * 64 + t];
        uB = xlh[(size_t)s1 * 64 + t];
    }

    for (int pp = 0; pp < pairs; ++pp) {
        int e = o0 + 2 * pp;
        float2 x0 = h2f(uA), x1 = h2f(uB);
        if (pp + 1 < pairs) {               // prefetch next pair's gathers
            int s0 = e_src[e + 2];
            int s1 = e_src[e + 3];
            uA = xlh[(size_t)s0 * 64 + t];
            uB = xlh[(size_t)s1 * 64 + t];
        }
        const unsigned int* er = ea_h + (size_t)e * 16;   // uniform
        float ex0 = 0.f, ey0 = 0.f, ex1 = 0.f, ey1 = 0.f;
        EPROJ(ex0, ey0, er)
        EPROJ(ex1, ey1, er + 16)
        epsx += ex0 + ex1; epsy += ey0 + ey1;
        float vx0 = x0.x + xri.x + ex0, vy0 = x0.y + xri.y + ey0;
        float vx1 = x1.x + xri.x + ex1, vy1 = x1.y + xri.y + ey1;
        vx0 = fmaxf(vx0, NEG_SLOPE * vx0);
        vy0 = fmaxf(vy0, NEG_SLOPE * vy0);
        vx1 = fmaxf(vx1, NEG_SLOPE * vx1);
        vy1 = fmaxf(vy1, NEG_SLOPE * vy1);
        float p0 = vx0 * attv.x + vy0 * attv.y;
        float p1 = vx1 * attv.x + vy1 * attv.y;
#pragma unroll
        for (int off = 32; off > 0; off >>= 1) {
            p0 += __shfl_xor(p0, off);
            p1 += __shfl_xor(p1, off);
        }
        float pm = fmaxf(p0, p1);
        if (pm > m + RESCALE_THR_LOG2) {
            float sc = exp2f(m - pm);
            accx *= sc; accy *= sc; denom *= sc;
            m = pm;
        }
        float wA = exp2f(p0 - m);
        float wB = exp2f(p1 - m);
        accx += wA * x0.x + wB * x1.x;
        accy += wA * x0.y + wB * x1.y;
        denom += wA + wB;
    }

    if (cnt & 1) {                          // tail edge
        int e = o1 - 1;
        int s = e_src[e];
        float2 x0 = h2f(xlh[(size_t)s * 64 + t]);
        const unsigned int* er = ea_h + (size_t)e * 16;
        float ex = 0.f, ey = 0.f;
        EPROJ(ex, ey, er)
        epsx += ex; epsy += ey;
        float vx = x0.x + xri.x + ex;
        float vy = x0.y + xri.y + ey;
        vx = fmaxf(vx, NEG_SLOPE * vx);
        vy = fmaxf(vy, NEG_SLOPE * vy);
        float p = vx * attv.x + vy * attv.y;
#pragma unroll
        for (int off = 32; off > 0; off >>= 1) p += __shfl_xor(p, off);
        if (p > m + RESCALE_THR_LOG2) {
            float sc = exp2f(m - p);
            accx *= sc; accy *= sc; denom *= sc;
            m = p;
        }
        float w = exp2f(p - m);
        accx += w * x0.x;
        accy += w * x0.y;
        denom += w;
    }
#undef EPROJ
#undef DOTP

    // ---- self-loop (last): loop_attr projection = mean of eproj ----
    float invdeg = 1.f / fmaxf((float)cnt, 1.f);
    float sx = xli.x + xri.x + epsx * invdeg;
    float sy = xli.y + xri.y + epsy * invdeg;
    sx = fmaxf(sx, NEG_SLOPE * sx);
    sy = fmaxf(sy, NEG_SLOPE * sy);
    float ps = sx * attv.x + sy * attv.y;
#pragma unroll
    for (int off = 32; off > 0; off >>= 1) ps += __shfl_xor(ps, off);

    float mm = fmaxf(m, ps);
    float wf = exp2f(m - mm);
    float ws = exp2f(ps - mm);
    denom = denom * wf + ws;
    accx = accx * wf + ws * xli.x;
    accy = accy * wf + ws * xli.y;

    float ox = accx / denom + bov.x;
    float oy = accy / denom + bov.y;
    float2 o;
    o.x = ox / (1.f + __expf(-ox));
    o.y = oy / (1.f + __expf(-oy));
    ((float2*)(hout + (size_t)i * HIP_H))[t] = o;
}

// ---------------- host launch ----------------
extern "C" void kernel_launch(void* const* d_in, const int* in_sizes, int n_in,
                              void* d_out, int out_size, void* d_ws, size_t ws_size,
                              hipStream_t stream) {
    const float* x      = (const float*)d_in[0];
    const int*   ei     = (const int*)d_in[1];
    const float* ea     = (const float*)d_in[2];
    const float* W_emb  = (const float*)d_in[3];
    const float* b_emb  = (const float*)d_in[4];
    const float* Wl1    = (const float*)d_in[5];
    const float* bl1    = (const float*)d_in[6];
    const float* Wr1    = (const float*)d_in[7];
    const float* We1    = (const float*)d_in[8];
    const float* att1   = (const float*)d_in[9];
    const float* bo1    = (const float*)d_in[10];
    const float* Wl2    = (const float*)d_in[11];
    const float* bl2    = (const float*)d_in[12];
    const float* Wr2    = (const float*)d_in[13];
    const float* We2    = (const float*)d_in[14];
    const float* att2   = (const float*)d_in[15];
    const float* bo2    = (const float*)d_in[16];
    float* out = (float*)d_out;

    char* p = (char*)d_ws;
    auto carve = [&](size_t bytes) {
        void* q = (void*)p;
        p += (bytes + 255) / 256 * 256;
        return q;
    };
    float* h        = (float*)carve((size_t)HIP_N * 128 * 4);
    unsigned int* xlh = (unsigned int*)carve((size_t)HIP_N * 64 * 4);
    unsigned int* xrh = (unsigned int*)carve((size_t)HIP_N * 64 * 4);
    unsigned int* ea_h = (unsigned int*)carve((size_t)HIP_E * 16 * 4);
    int*   deg      = (int*)carve((size_t)HIP_N * 4);
    int*   offs     = (int*)carve((size_t)(HIP_N + 1) * 4);
    int*   cursor   = (int*)carve((size_t)HIP_N * 4);
    int*   e_src    = (int*)carve((size_t)HIP_E * 4);
    int*   flag     = (int*)carve(256);
    int*   bsums    = (int*)carve((size_t)SCAN_NB * 4);
    unsigned int* Wepk1 = (unsigned int*)carve(2048 * 4);
    unsigned int* Wepk2 = (unsigned int*)carve(2048 * 4);
    unsigned short* Wt1 = (unsigned short*)carve(256 * 128 * 2);
    unsigned short* Wt2 = (unsigned short*)carve(256 * 128 * 2);
    float* b1       = (float*)carve(256 * 4);
    float* b2       = (float*)carve(256 * 4);

    hipMemsetAsync(flag, 0, 4, stream);

    // ONE prep dispatch: compose->Wt1(f16,T), Wt2 transpose, biases,
    // We packs, edge-dtype detect, deg zeroing
    k_prep<<<PREP_NB, 128, 0, stream>>>(W_emb, b_emb, Wl1, bl1, Wr1,
                                        Wl2, bl2, Wr2, We1, We2,
                                        ei, flag, Wt1, Wt2, b1, b2,
                                        Wepk1, Wepk2, deg);

    k_hist<<<(HIP_E + 255) / 256, 256, 0, stream>>>(ei, flag, deg);
    k_scan1<<<SCAN_NB, 256, 0, stream>>>(deg, bsums);
    k_scan3<<<SCAN_NB, 1024, 0, stream>>>(deg, bsums, offs, cursor);

    // fat dispatch: layer-1 MFMA lin (composed weights, input x) + CSR scatter
    k_fat1<<<LINM + SCATB, 256, 0, stream>>>(x, Wt1, b1, xlh, xrh,
                                             ei, flag, cursor, e_src, ea, ea_h);

    // ----- layer 1 -----
    k_node_fused<<<HIP_N, 64, 0, stream>>>(offs, e_src, ea_h, Wepk1, att1,
                                           xlh, xrh, bo1, h);
    // ----- layer 2 -----
    k_linm<<<LINM, 256, 0, stream>>>(h, Wt2, b2, xlh, xrh);
    k_node_fused<<<HIP_N, 64, 0, stream>>>(offs, e_src, ea_h, Wepk2, att2,
                                           xlh, xrh, bo2, out);
}

// Round 18
// 436.470 us; speedup vs baseline: 1.1627x; 1.0159x over previous
//
#include <hip/hip_runtime.h>
#include <hip/hip_bf16.h>
#include <math.h>

// HelicalGNNFrontend: 2-layer GATv2 (heads=1, self-loops, mean loop edge_attr)
// N=50000, E=800000, NODE_DIM=HID=128, EDGE_DIM=32.
//
// Round 18: (a) edge-dtype self-detection per wave (probe ei[2e+1]: all-zero
// iff int64) -> flag / k_detect / memset eliminated (9 -> 8 graph nodes);
// (b) inter-layer h stored packed f16 (fused-1 epilogue pkh; layer-2 MFMA
// loads A-frag as uint4 of 8 halves; ~38 MB traffic + 4 cvt/k-step saved).
// Everything else frozen from R17.

#define HIP_N 50000
#define HIP_E 800000
#define HIP_H 128
#define HIP_ED 32
#define NEG_SLOPE 0.2f
#define RESCALE_THR_LOG2 11.5416f   // 8 / ln2
#define LINM 3125                   // 50000 / 16 M-tiles
#define SCATB ((HIP_E + 255) / 256) // 3125 scatter blocks
#define INV_LN2 1.4426950408889634f

typedef __fp16 h2 __attribute__((ext_vector_type(2)));
typedef _Float16 half8 __attribute__((ext_vector_type(8)));
typedef float f32x4 __attribute__((ext_vector_type(4)));

__device__ __forceinline__ h2 u2h(unsigned int u) {
    union { unsigned int u; h2 h; } c; c.u = u; return c.h;
}
__device__ __forceinline__ unsigned int pkh(float a, float b) {
    union { h2 h; unsigned int u; } c;
    c.h = __builtin_amdgcn_cvt_pkrtz(a, b);
    return c.u;
}
__device__ __forceinline__ float2 h2f(unsigned int u) {
    h2 h = u2h(u);
    return make_float2((float)h.x, (float)h.y);
}
__device__ __forceinline__ half8 u4h8(uint4 u) {
    union { uint4 u; half8 h; } c; c.u = u; return c.h;
}

__device__ __forceinline__ int fetch_idx(const int* __restrict__ ei, int is32, long long pos) {
    return is32 ? ei[pos] : ei[2 * pos];  // little-endian low word for int64
}

// per-wave edge-dtype detect: probe ei[2e+1] (valid flat index in BOTH
// layouts). int64 -> high words, all zero. int32 -> node ids, ~never all 0.
__device__ __forceinline__ int wave_is32(const int* __restrict__ ei, int e) {
    int probe = (e < HIP_E) ? ei[2 * (long long)e + 1] : 0;
    return __any(probe != 0);
}

// ---------------- mega prep kernel (128 threads/block) ----------------
// blocks [0,256): compose W_emb@{Wl1,Wr1} row -> Wt1 transposed f16
// blocks 256..259: biases
// blocks [260,388): layer-2 weight transpose -> Wt2 f16
// blocks [388,420): We1/We2 pack -> Wepk1/2
// blocks [420, ...): zero deg
#define PREP_NB (420 + (HIP_N + 127) / 128)

__global__ __launch_bounds__(128) void k_prep(
    const float* __restrict__ Wemb, const float* __restrict__ bemb,
    const float* __restrict__ Wl1, const float* __restrict__ bl1,
    const float* __restrict__ Wr1,
    const float* __restrict__ Wl2, const float* __restrict__ bl2,
    const float* __restrict__ Wr2,
    const float* __restrict__ We1, const float* __restrict__ We2,
    unsigned short* __restrict__ Wt1, unsigned short* __restrict__ Wt2,
    float* __restrict__ b1, float* __restrict__ b2,
    unsigned int* __restrict__ Wepk1, unsigned int* __restrict__ Wepk2,
    int* __restrict__ deg) {
    int b = blockIdx.x, t = threadIdx.x;
    if (b < 256) {
        int r = b & 127;
        const float* W = (b < 128) ? Wl1 : Wr1;
        int nofs = (b < 128) ? 0 : 128;
        float acc = 0.f;
        for (int k = 0; k < 128; ++k) acc += Wemb[r * 128 + k] * W[k * 128 + t];
        union { __fp16 h; unsigned short s; } cv;
        cv.h = (__fp16)acc;
        Wt1[(size_t)(nofs + t) * 128 + r] = cv.s;   // Wt1[n][k] = Wf[k][n]
    } else if (b == 256) {
        float acc = bl1[t];
        for (int k = 0; k < 128; ++k) acc += bemb[k] * Wl1[k * 128 + t];
        b1[t] = acc;
    } else if (b == 257) {
        float acc = 0.f;
        for (int k = 0; k < 128; ++k) acc += bemb[k] * Wr1[k * 128 + t];
        b1[128 + t] = acc;
    } else if (b == 258) {
        b2[t] = bl2[t];
    } else if (b == 259) {
        b2[128 + t] = 0.f;
    } else if (b < 388) {
        int k = b - 260;                            // row of Wl2/Wr2
        float vl = Wl2[k * 128 + t], vr = Wr2[k * 128 + t];
        union { __fp16 h; unsigned short s; } c1, c2;
        c1.h = (__fp16)vl; c2.h = (__fp16)vr;
        Wt2[(size_t)t * 128 + k] = c1.s;
        Wt2[(size_t)(128 + t) * 128 + k] = c2.s;
    } else if (b < 420) {
        int idx = (b - 388) * 128 + t;              // [0, 4096)
        const float* We = (idx < 2048) ? We1 : We2;
        unsigned int* P = (idx < 2048) ? Wepk1 : Wepk2;
        int r = idx & 2047;
        int d2 = r >> 7, rem = r & 127;
        int j = rem >> 6, tt = rem & 63;
        int col = 2 * tt + j;
        P[r] = pkh(We[(2 * d2) * 128 + col], We[(2 * d2 + 1) * 128 + col]);
    } else {
        int i = (b - 420) * 128 + t;
        if (i < HIP_N) deg[i] = 0;
    }
}

// ---------------- CSR build ----------------
__global__ void k_hist(const int* __restrict__ ei, int* __restrict__ deg) {
    int e = blockIdx.x * blockDim.x + threadIdx.x;
    int is32 = wave_is32(ei, e);
    if (e < HIP_E) {
        int d = fetch_idx(ei, is32, (long long)HIP_E + e);
        atomicAdd(&deg[d], 1);
    }
}

#define SCAN_TILE 1024
#define SCAN_NB ((HIP_N + SCAN_TILE - 1) / SCAN_TILE)   // 49

__global__ __launch_bounds__(256) void k_scan1(const int* __restrict__ deg,
                                               int* __restrict__ bsums) {
    __shared__ int ws[4];
    int b = blockIdx.x, t = threadIdx.x;
    int base = b * SCAN_TILE;
    int v = 0;
#pragma unroll
    for (int j = 0; j < 4; ++j) {
        int i = base + t + 256 * j;
        if (i < HIP_N) v += deg[i];
    }
#pragma unroll
    for (int off = 32; off > 0; off >>= 1) v += __shfl_xor(v, off);
    int lane = t & 63, wid = t >> 6;
    if (lane == 0) ws[wid] = v;
    __syncthreads();
    if (t == 0) bsums[b] = ws[0] + ws[1] + ws[2] + ws[3];
}

// scan3 with folded scan2: block computes its own bsums prefix
__global__ __launch_bounds__(1024) void k_scan3(const int* __restrict__ deg,
                                                const int* __restrict__ bsums,
                                                int* __restrict__ offs,
                                                int* __restrict__ cursor) {
    __shared__ int wsum[16];
    __shared__ int bbase_sh;
    int b = blockIdx.x, t = threadIdx.x;
    int i = b * SCAN_TILE + t;
    int lane = t & 63, wid = t >> 6;
    if (wid == 0) {                      // prefix of bsums[0..b-1]
        int v = (lane < SCAN_NB && lane < b) ? bsums[lane] : 0;
#pragma unroll
        for (int off = 32; off > 0; off >>= 1) v += __shfl_xor(v, off);
        if (lane == 0) bbase_sh = v;
    }
    int v = (i < HIP_N) ? deg[i] : 0;
    int incl = v;
#pragma unroll
    for (int off = 1; off < 64; off <<= 1) {
        int u = __shfl_up(incl, off);
        if (lane >= off) incl += u;
    }
    if (lane == 63) wsum[wid] = incl;
    __syncthreads();
    if (wid == 0 && lane < 16) {
        int w = wsum[lane];
#pragma unroll
        for (int off = 1; off < 16; off <<= 1) {
            int u = __shfl_up(w, off);
            if (lane >= off) w += u;
        }
        wsum[lane] = w;   // inclusive over waves
    }
    __syncthreads();
    int baseadd = bbase_sh + (wid > 0 ? wsum[wid - 1] : 0);
    int excl = baseadd + incl - v;
    if (i < HIP_N) {
        offs[i] = excl;
        cursor[i] = excl;
        if (i == HIP_N - 1) offs[HIP_N] = excl + v;
    }
}

// ---------------- MFMA dual-GEMM body (templated A dtype) ----------------
// out[xl|xr] = A[50k,128] @ Wt^T (Wt [256][128] f16) + bias[256]
template <bool AHALF>
__device__ __forceinline__ void linm_body(const float* __restrict__ Af,
                                          const unsigned int* __restrict__ Ah,
                                          const unsigned short* __restrict__ Wt,
                                          const float* __restrict__ bias,
                                          unsigned int* __restrict__ xlh,
                                          unsigned int* __restrict__ xrh, int blk) {
    int tid = threadIdx.x;
    int wid = tid >> 6, l = tid & 63;
    int li = l & 15, lk = l >> 4;          // A row / C col = li; k-group = lk
    int rowA = blk * 16 + li;

    f32x4 acc0 = {0.f, 0.f, 0.f, 0.f};
    f32x4 acc1 = {0.f, 0.f, 0.f, 0.f};
    f32x4 acc2 = {0.f, 0.f, 0.f, 0.f};
    f32x4 acc3 = {0.f, 0.f, 0.f, 0.f};

#pragma unroll
    for (int ks = 0; ks < 4; ++ks) {
        int kb = ks * 32 + lk * 8;
        half8 afrag;
        if (AHALF) {
            afrag = u4h8(*(const uint4*)(Ah + (size_t)rowA * 64 + (kb >> 1)));
        } else {
            const float4* ap = (const float4*)(Af + (size_t)rowA * 128 + kb);
            float4 a0 = ap[0], a1 = ap[1];
            afrag = u4h8(make_uint4(pkh(a0.x, a0.y), pkh(a0.z, a0.w),
                                    pkh(a1.x, a1.y), pkh(a1.z, a1.w)));
        }
        int nbase = wid * 64 + li;
        half8 b0 = u4h8(*(const uint4*)(Wt + (size_t)(nbase +  0) * 128 + kb));
        half8 b1 = u4h8(*(const uint4*)(Wt + (size_t)(nbase + 16) * 128 + kb));
        half8 b2 = u4h8(*(const uint4*)(Wt + (size_t)(nbase + 32) * 128 + kb));
        half8 b3 = u4h8(*(const uint4*)(Wt + (size_t)(nbase + 48) * 128 + kb));
        acc0 = __builtin_amdgcn_mfma_f32_16x16x32_f16(afrag, b0, acc0, 0, 0, 0);
        acc1 = __builtin_amdgcn_mfma_f32_16x16x32_f16(afrag, b1, acc1, 0, 0, 0);
        acc2 = __builtin_amdgcn_mfma_f32_16x16x32_f16(afrag, b2, acc2, 0, 0, 0);
        acc3 = __builtin_amdgcn_mfma_f32_16x16x32_f16(afrag, b3, acc3, 0, 0, 0);
    }

    bool even = !(l & 1);
#pragma unroll
    for (int nt = 0; nt < 4; ++nt) {
        f32x4 a = (nt == 0) ? acc0 : (nt == 1) ? acc1 : (nt == 2) ? acc2 : acc3;
        int n = wid * 64 + nt * 16 + li;
        float bb = bias[n];
        unsigned int* outp = (n < 128) ? xlh : xrh;
        int nn = n & 127;
#pragma unroll
        for (int r = 0; r < 4; ++r) {
            int rowg = blk * 16 + lk * 4 + r;
            float v = a[r] + bb;
            float v1 = __shfl_down(v, 1);
            if (even) outp[(size_t)rowg * 64 + (nn >> 1)] = pkh(v, v1);
        }
    }
}

// scatter body: e_src[pos]=src, ea_h[pos]= half2-packed ea row (64B)
__device__ __forceinline__ void scatter_body(const int* __restrict__ ei, int is32,
                                             int* __restrict__ cursor,
                                             int* __restrict__ e_src,
                                             const float* __restrict__ ea,
                                             unsigned int* __restrict__ ea_h, int e) {
    if (e < HIP_E) {
        int s = fetch_idx(ei, is32, e);
        int d = fetch_idx(ei, is32, (long long)HIP_E + e);
        int pos = atomicAdd(&cursor[d], 1);
        e_src[pos] = s;
        const float4* src4 = (const float4*)(ea + (size_t)e * HIP_ED);
        float4 s0 = src4[0], s1 = src4[1], s2 = src4[2], s3 = src4[3];
        float4 s4 = src4[4], s5 = src4[5], s6 = src4[6], s7 = src4[7];
        uint4* dst = (uint4*)(ea_h + (size_t)pos * 16);
        dst[0] = make_uint4(pkh(s0.x, s0.y), pkh(s0.z, s0.w),
                            pkh(s1.x, s1.y), pkh(s1.z, s1.w));
        dst[1] = make_uint4(pkh(s2.x, s2.y), pkh(s2.z, s2.w),
                            pkh(s3.x, s3.y), pkh(s3.z, s3.w));
        dst[2] = make_uint4(pkh(s4.x, s4.y), pkh(s4.z, s4.w),
                            pkh(s5.x, s5.y), pkh(s5.z, s5.w));
        dst[3] = make_uint4(pkh(s6.x, s6.y), pkh(s6.z, s6.w),
                            pkh(s7.x, s7.y), pkh(s7.z, s7.w));
    }
}

// fat kernel: blocks [0, LINM) do layer-1 MFMA lin; rest scatter
__global__ __launch_bounds__(256) void k_fat1(
    const float* __restrict__ x, const unsigned short* __restrict__ Wt1,
    const float* __restrict__ b1,
    unsigned int* __restrict__ xlh, unsigned int* __restrict__ xrh,
    const int* __restrict__ ei,
    int* __restrict__ cursor, int* __restrict__ e_src,
    const float* __restrict__ ea, unsigned int* __restrict__ ea_h) {
    if (blockIdx.x < LINM) {
        linm_body<false>(x, nullptr, Wt1, b1, xlh, xrh, blockIdx.x);
    } else {
        int e = (blockIdx.x - LINM) * 256 + threadIdx.x;
        int is32 = wave_is32(ei, e);
        scatter_body(ei, is32, cursor, e_src, ea, ea_h, e);
    }
}

// layer-2 lin: A = packed-f16 h
__global__ __launch_bounds__(256) void k_linm(const unsigned int* __restrict__ hh,
                                              const unsigned short* __restrict__ Wt,
                                              const float* __restrict__ bias,
                                              unsigned int* __restrict__ xlh,
                                              unsigned int* __restrict__ xrh) {
    linm_body<true>(nullptr, hh, Wt, bias, xlh, xrh, blockIdx.x);
}

// ---------------- fused per-node online softmax + aggregation ----------------
// (frozen) ONE 64-thread block per node; scalar s_load edge stream; f16
// packed xl/xr gathers; 32x fdot2 eproj; exp2 logits; 2-wide pipeline.
// OUTH=1: write packed f16 (inter-layer h); OUTH=0: write fp32 (final out).
template <int OUTH>
__global__ __launch_bounds__(64) void k_node_fused(
    const int* __restrict__ offs, const int* __restrict__ e_src,
    const unsigned int* __restrict__ ea_h,
    const unsigned int* __restrict__ Wepk, const float* __restrict__ att,
    const unsigned int* __restrict__ xlh, const unsigned int* __restrict__ xrh,
    const float* __restrict__ bo,
    unsigned int* __restrict__ houth, float* __restrict__ houtf) {
    int i = blockIdx.x;           // uniform node id
    int t = threadIdx.x;          // lane, owns feature dims (2t, 2t+1)

    h2 wx00 = u2h(Wepk[ 0*128 + t]),      wy00 = u2h(Wepk[ 0*128 + 64 + t]);
    h2 wx01 = u2h(Wepk[ 1*128 + t]),      wy01 = u2h(Wepk[ 1*128 + 64 + t]);
    h2 wx02 = u2h(Wepk[ 2*128 + t]),      wy02 = u2h(Wepk[ 2*128 + 64 + t]);
    h2 wx03 = u2h(Wepk[ 3*128 + t]),      wy03 = u2h(Wepk[ 3*128 + 64 + t]);
    h2 wx04 = u2h(Wepk[ 4*128 + t]),      wy04 = u2h(Wepk[ 4*128 + 64 + t]);
    h2 wx05 = u2h(Wepk[ 5*128 + t]),      wy05 = u2h(Wepk[ 5*128 + 64 + t]);
    h2 wx06 = u2h(Wepk[ 6*128 + t]),      wy06 = u2h(Wepk[ 6*128 + 64 + t]);
    h2 wx07 = u2h(Wepk[ 7*128 + t]),      wy07 = u2h(Wepk[ 7*128 + 64 + t]);
    h2 wx08 = u2h(Wepk[ 8*128 + t]),      wy08 = u2h(Wepk[ 8*128 + 64 + t]);
    h2 wx09 = u2h(Wepk[ 9*128 + t]),      wy09 = u2h(Wepk[ 9*128 + 64 + t]);
    h2 wx10 = u2h(Wepk[10*128 + t]),      wy10 = u2h(Wepk[10*128 + 64 + t]);
    h2 wx11 = u2h(Wepk[11*128 + t]),      wy11 = u2h(Wepk[11*128 + 64 + t]);
    h2 wx12 = u2h(Wepk[12*128 + t]),      wy12 = u2h(Wepk[12*128 + 64 + t]);
    h2 wx13 = u2h(Wepk[13*128 + t]),      wy13 = u2h(Wepk[13*128 + 64 + t]);
    h2 wx14 = u2h(Wepk[14*128 + t]),      wy14 = u2h(Wepk[14*128 + 64 + t]);
    h2 wx15 = u2h(Wepk[15*128 + t]),      wy15 = u2h(Wepk[15*128 + 64 + t]);

    float2 attv = ((const float2*)att)[t];
    attv.x *= INV_LN2; attv.y *= INV_LN2;   // exp2-domain logits
    float2 bov  = ((const float2*)bo)[t];
    float2 xri  = h2f(xrh[(size_t)i * 64 + t]);
    float2 xli  = h2f(xlh[(size_t)i * 64 + t]);

    float m = -1e30f;
    float denom = 0.f;
    float accx = 0.f, accy = 0.f;
    float epsx = 0.f, epsy = 0.f;   // sum of per-edge eproj (for self-loop)

    int o0 = offs[i], o1 = offs[i + 1];     // uniform -> s_load
    int cnt = o1 - o0;
    int pairs = cnt >> 1;

#define DOTP(EX, EY, U, K)                                            \
    EX = __builtin_amdgcn_fdot2(u2h(U), wx##K, EX, false);            \
    EY = __builtin_amdgcn_fdot2(u2h(U), wy##K, EY, false);

#define EPROJ(EX, EY, P)                                              \
    {                                                                 \
        uint4 q0 = ((const uint4*)(P))[0];                            \
        uint4 q1 = ((const uint4*)(P))[1];                            \
        uint4 q2 = ((const uint4*)(P))[2];                            \
        uint4 q3 = ((const uint4*)(P))[3];                            \
        DOTP(EX, EY, q0.x, 00) DOTP(EX, EY, q0.y, 01)                 \
        DOTP(EX, EY, q0.z, 02) DOTP(EX, EY, q0.w, 03)                 \
        DOTP(EX, EY, q1.x, 04) DOTP(EX, EY, q1.y, 05)                 \
        DOTP(EX, EY, q1.z, 06) DOTP(EX, EY, q1.w, 07)                 \
        DOTP(EX, EY, q2.x, 08) DOTP(EX, EY, q2.y, 09)                 \
        DOTP(EX, EY, q2.z, 10) DOTP(EX, EY, q2.w, 11)                 \
        DOTP(EX, EY, q3.x, 12) DOTP(EX, EY, q3.y, 13)                 \
        DOTP(EX, EY, q3.z, 14) DOTP(EX, EY, q3.w, 15)                 \
    }

    unsigned int uA = 0, uB = 0;
    if (pairs > 0) {
        int s0 = e_src[o0];                 // uniform -> s_load
        int s1 = e_src[o0 + 1];
        uA = xlh[(size_t)s0 * 64 + t];
        uB = xlh[(size_t)s1 * 64 + t];
    }

    for (int pp = 0; pp < pairs; ++pp) {
        int e = o0 + 2 * pp;
        float2 x0 = h2f(uA), x1 = h2f(uB);
        if (pp + 1 < pairs) {               // prefetch next pair's gathers
            int s0 = e_src[e + 2];
            int s1 = e_src[e + 3];
            uA = xlh[(size_t)s0 * 64 + t];
            uB = xlh[(size_t)s1 * 64 + t];
        }
        const unsigned int* er = ea_h + (size_t)e * 16;   // uniform
        float ex0 = 0.f, ey0 = 0.f, ex1 = 0.f, ey1 = 0.f;
        EPROJ(ex0, ey0, er)
        EPROJ(ex1, ey1, er + 16)
        epsx += ex0 + ex1; epsy += ey0 + ey1;
        float vx0 = x0.x + xri.x + ex0, vy0 = x0.y + xri.y + ey0;
        float vx1 = x1.x + xri.x + ex1, vy1 = x1.y + xri.y + ey1;
        vx0 = fmaxf(vx0, NEG_SLOPE * vx0);
        vy0 = fmaxf(vy0, NEG_SLOPE * vy0);
        vx1 = fmaxf(vx1, NEG_SLOPE * vx1);
        vy1 = fmaxf(vy1, NEG_SLOPE * vy1);
        float p0 = vx0 * attv.x + vy0 * attv.y;
        float p1 = vx1 * attv.x + vy1 * attv.y;
#pragma unroll
        for (int off = 32; off > 0; off >>= 1) {
            p0 += __shfl_xor(p0, off);
            p1 += __shfl_xor(p1, off);
        }
        float pm = fmaxf(p0, p1);
        if (pm > m + RESCALE_THR_LOG2) {
            float sc = exp2f(m - pm);
            accx *= sc; accy *= sc; denom *= sc;
            m = pm;
        }
        float wA = exp2f(p0 - m);
        float wB = exp2f(p1 - m);
        accx += wA * x0.x + wB * x1.x;
        accy += wA * x0.y + wB * x1.y;
        denom += wA + wB;
    }

    if (cnt & 1) {                          // tail edge
        int e = o1 - 1;
        int s = e_src[e];
        float2 x0 = h2f(xlh[(size_t)s * 64 + t]);
        const unsigned int* er = ea_h + (size_t)e * 16;
        float ex = 0.f, ey = 0.f;
        EPROJ(ex, ey, er)
        epsx += ex; epsy += ey;
        float vx = x0.x + xri.x + ex;
        float vy = x0.y + xri.y + ey;
        vx = fmaxf(vx, NEG_SLOPE * vx);
        vy = fmaxf(vy, NEG_SLOPE * vy);
        float p = vx * attv.x + vy * attv.y;
#pragma unroll
        for (int off = 32; off > 0; off >>= 1) p += __shfl_xor(p, off);
        if (p > m + RESCALE_THR_LOG2) {
            float sc = exp2f(m - p);
            accx *= sc; accy *= sc; denom *= sc;
            m = p;
        }
        float w = exp2f(p - m);
        accx += w * x0.x;
        accy += w * x0.y;
        denom += w;
    }
#undef EPROJ
#undef DOTP

    // ---- self-loop (last): loop_attr projection = mean of eproj ----
    float invdeg = 1.f / fmaxf((float)cnt, 1.f);
    float sx = xli.x + xri.x + epsx * invdeg;
    float sy = xli.y + xri.y + epsy * invdeg;
    sx = fmaxf(sx, NEG_SLOPE * sx);
    sy = fmaxf(sy, NEG_SLOPE * sy);
    float ps = sx * attv.x + sy * attv.y;
#pragma unroll
    for (int off = 32; off > 0; off >>= 1) ps += __shfl_xor(ps, off);

    float mm = fmaxf(m, ps);
    float wf = exp2f(m - mm);
    float ws = exp2f(ps - mm);
    denom = denom * wf + ws;
    accx = accx * wf + ws * xli.x;
    accy = accy * wf + ws * xli.y;

    float ox = accx / denom + bov.x;
    float oy = accy / denom + bov.y;
    float sox = ox / (1.f + __expf(-ox));
    float soy = oy / (1.f + __expf(-oy));
    if (OUTH) {
        houth[(size_t)i * 64 + t] = pkh(sox, soy);
    } else {
        float2 o; o.x = sox; o.y = soy;
        ((float2*)(houtf + (size_t)i * HIP_H))[t] = o;
    }
}

// ---------------- host launch ----------------
extern "C" void kernel_launch(void* const* d_in, const int* in_sizes, int n_in,
                              void* d_out, int out_size, void* d_ws, size_t ws_size,
                              hipStream_t stream) {
    const float* x      = (const float*)d_in[0];
    const int*   ei     = (const int*)d_in[1];
    const float* ea     = (const float*)d_in[2];
    const float* W_emb  = (const float*)d_in[3];
    const float* b_emb  = (const float*)d_in[4];
    const float* Wl1    = (const float*)d_in[5];
    const float* bl1    = (const float*)d_in[6];
    const float* Wr1    = (const float*)d_in[7];
    const float* We1    = (const float*)d_in[8];
    const float* att1   = (const float*)d_in[9];
    const float* bo1    = (const float*)d_in[10];
    const float* Wl2    = (const float*)d_in[11];
    const float* bl2    = (const float*)d_in[12];
    const float* Wr2    = (const float*)d_in[13];
    const float* We2    = (const float*)d_in[14];
    const float* att2   = (const float*)d_in[15];
    const float* bo2    = (const float*)d_in[16];
    float* out = (float*)d_out;

    char* p = (char*)d_ws;
    auto carve = [&](size_t bytes) {
        void* q = (void*)p;
        p += (bytes + 255) / 256 * 256;
        return q;
    };
    unsigned int* hh  = (unsigned int*)carve((size_t)HIP_N * 64 * 4);
    unsigned int* xlh = (unsigned int*)carve((size_t)HIP_N * 64 * 4);
    unsigned int* xrh = (unsigned int*)carve((size_t)HIP_N * 64 * 4);
    unsigned int* ea_h = (unsigned int*)carve((size_t)HIP_E * 16 * 4);
    int*   deg      = (int*)carve((size_t)HIP_N * 4);
    int*   offs     = (int*)carve((size_t)(HIP_N + 1) * 4);
    int*   cursor   = (int*)carve((size_t)HIP_N * 4);
    int*   e_src    = (int*)carve((size_t)HIP_E * 4);
    int*   bsums    = (int*)carve((size_t)SCAN_NB * 4);
    unsigned int* Wepk1 = (unsigned int*)carve(2048 * 4);
    unsigned int* Wepk2 = (unsigned int*)carve(2048 * 4);
    unsigned short* Wt1 = (unsigned short*)carve(256 * 128 * 2);
    unsigned short* Wt2 = (unsigned short*)carve(256 * 128 * 2);
    float* b1       = (float*)carve(256 * 4);
    float* b2       = (float*)carve(256 * 4);

    // ONE prep dispatch: compose->Wt1(f16,T), Wt2 transpose, biases,
    // We packs, deg zeroing (edge dtype now self-detected per wave)
    k_prep<<<PREP_NB, 128, 0, stream>>>(W_emb, b_emb, Wl1, bl1, Wr1,
                                        Wl2, bl2, Wr2, We1, We2,
                                        Wt1, Wt2, b1, b2,
                                        Wepk1, Wepk2, deg);

    k_hist<<<(HIP_E + 255) / 256, 256, 0, stream>>>(ei, deg);
    k_scan1<<<SCAN_NB, 256, 0, stream>>>(deg, bsums);
    k_scan3<<<SCAN_NB, 1024, 0, stream>>>(deg, bsums, offs, cursor);

    // fat dispatch: layer-1 MFMA lin (composed weights, input x) + CSR scatter
    k_fat1<<<LINM + SCATB, 256, 0, stream>>>(x, Wt1, b1, xlh, xrh,
                                             ei, cursor, e_src, ea, ea_h);

    // ----- layer 1 (h written packed f16) -----
    k_node_fused<1><<<HIP_N, 64, 0, stream>>>(offs, e_src, ea_h, Wepk1, att1,
                                              xlh, xrh, bo1, hh, nullptr);
    // ----- layer 2 -----
    k_linm<<<LINM, 256, 0, stream>>>(hh, Wt2, b2, xlh, xrh);
    k_node_fused<0><<<HIP_N, 64, 0, stream>>>(offs, e_src, ea_h, Wepk2, att2,
                                              xlh, xrh, bo2, nullptr, out);
}